// Round 3
// baseline (299.664 us; speedup 1.0000x reference)
//
#include <hip/hip_runtime.h>
#include <hip/hip_bf16.h>

#define N_PTS   65536
#define PBLK    16                 // points per block
#define NBLK    (N_PTS / PBLK)     // 4096 blocks
#define HID     256

typedef __attribute__((ext_vector_type(8))) short short8;   // 8 bf16 = 4 VGPR
typedef __attribute__((ext_vector_type(4))) short short4v;  // 4 bf16 = 8 B
typedef __attribute__((ext_vector_type(4))) float floatx4;  // MFMA C/D

__device__ __forceinline__ short f2bf(float x) {            // compiler -> v_cvt_pk_bf16_f32
    union { __hip_bfloat16 b; short s; } u;
    u.b = __float2bfloat16(x);
    return u.s;
}
__device__ __forceinline__ float bf2f(short h) {
    union { unsigned u; float f; } v;
    v.u = ((unsigned)(unsigned short)h) << 16;
    return v.f;
}
__device__ __forceinline__ float fast_tanh(float x) {
    float e = __expf(2.0f * x);
    return 1.0f - 2.0f / (e + 1.0f);
}

// ---- weight transpose+convert: Wt[L][n][k] = bf16(W_L[k][n]) ----
__global__ __launch_bounds__(256) void conv_w(
    const float* __restrict__ W1, const float* __restrict__ W2,
    const float* __restrict__ W3, const float* __restrict__ W4,
    short* __restrict__ Wt)
{
    int layer = blockIdx.x >> 8;
    int n     = blockIdx.x & 255;
    const float* W = (layer == 0) ? W1 : (layer == 1) ? W2 : (layer == 2) ? W3 : W4;
    int k = threadIdx.x;
    Wt[((layer << 8) + n) * 256 + k] = f2bf(W[k * 256 + n]);
}

__global__ __launch_bounds__(256, 3) void pinn_main(
    const float* __restrict__ vect, const int* __restrict__ vals,
    const float* __restrict__ W0, const float* __restrict__ b0,
    const float* __restrict__ b1, const float* __restrict__ b2,
    const float* __restrict__ b3, const float* __restrict__ b4,
    const float* __restrict__ W5, const float* __restrict__ b5,
    const short* __restrict__ Wt, float* __restrict__ partials)
{
    // H[ch][pt][k] bf16, col-swizzled:  elem = ch*4096 + pt*256 + (k ^ ((pt&7)<<3))
    __shared__ __align__(16) short Hs[5 * PBLK * HID];   // 40 KB
    __shared__ float red[4][5];

    const int tid   = threadIdx.x;
    const int wave  = tid >> 6;
    const int lane  = tid & 63;
    const int g     = lane >> 4;          // lane group 0..3
    const int l15   = lane & 15;
    const int pbase = blockIdx.x * PBLK;
    const int swzB  = (l15 & 7) << 3;     // row-swizzle for this lane's H row/write row

    // ---------------- layer 0: 2 -> 256 (fp32 VALU, cheap) ----------------
    {
        const int c0 = lane * 4;
        float4 wx4 = *(const float4*)(W0 + c0);          // W0[0][c]
        float4 wy4 = *(const float4*)(W0 + HID + c0);    // W0[1][c]
        float4 bb4 = *(const float4*)(b0 + c0);
        float wx[4] = {wx4.x, wx4.y, wx4.z, wx4.w};
        float wy[4] = {wy4.x, wy4.y, wy4.z, wy4.w};
        float bb[4] = {bb4.x, bb4.y, bb4.z, bb4.w};
        #pragma unroll
        for (int p = 0; p < 4; ++p) {
            int pt = 4 * wave + p;
            float x = vect[(pbase + pt) * 2 + 0];
            float y = vect[(pbase + pt) * 2 + 1];
            short4v hv, hgx, hgy, hxx, hyy;
            #pragma unroll
            for (int q = 0; q < 4; ++q) {
                float z  = x * wx[q] + y * wy[q] + bb[q];
                float a  = fast_tanh(z);
                float s  = 1.0f - a * a;
                float gx = s * wx[q];
                float gy = s * wy[q];
                hv[q]  = f2bf(a);
                hgx[q] = f2bf(gx);
                hgy[q] = f2bf(gy);
                hxx[q] = f2bf(-2.0f * a * gx * wx[q]);
                hyy[q] = f2bf(-2.0f * a * gy * wy[q]);
            }
            int idx = pt * 256 + (c0 ^ ((pt & 7) << 3));
            *(short4v*)&Hs[0 * 4096 + idx] = hv;
            *(short4v*)&Hs[1 * 4096 + idx] = hgx;
            *(short4v*)&Hs[2 * 4096 + idx] = hgy;
            *(short4v*)&Hs[3 * 4096 + idx] = hxx;
            *(short4v*)&Hs[4 * 4096 + idx] = hyy;
        }
    }

    // ---------------- hidden layers 1..4 via MFMA (D = W_tile * H^T) ----------------
    const float* bs[4] = {b1, b2, b3, b4};

    #pragma unroll
    for (int L = 0; L < 4; ++L) {
        floatx4 acc[5][4];
        #pragma unroll
        for (int ch = 0; ch < 5; ++ch)
            #pragma unroll
            for (int cf = 0; cf < 4; ++cf)
                acc[ch][cf] = (floatx4){0.f, 0.f, 0.f, 0.f};

        // A-frag (W) base pointers: A[row = n0+l15][k = g*8 + ks*32 + j]
        const short* wp0 = Wt + L * 65536 + ((wave * 4 + 0) * 16 + l15) * 256 + g * 8;
        const short* wp1 = wp0 + 16 * 256;
        const short* wp2 = wp1 + 16 * 256;
        const short* wp3 = wp2 + 16 * 256;

        __syncthreads();   // H writes from previous stage visible

        #pragma unroll
        for (int ks = 0; ks < 8; ++ks) {
            const int ko = (g * 8 + ks * 32) ^ swzB;   // swizzled H col window
            short8 hf[5], wf[4];
            #pragma unroll
            for (int ch = 0; ch < 5; ++ch)
                hf[ch] = *(const short8*)&Hs[ch * 4096 + l15 * 256 + ko];
            wf[0] = *(const short8*)(wp0 + ks * 32);
            wf[1] = *(const short8*)(wp1 + ks * 32);
            wf[2] = *(const short8*)(wp2 + ks * 32);
            wf[3] = *(const short8*)(wp3 + ks * 32);
            #pragma unroll
            for (int ch = 0; ch < 5; ++ch)
                #pragma unroll
                for (int cf = 0; cf < 4; ++cf)
                    acc[ch][cf] = __builtin_amdgcn_mfma_f32_16x16x32_bf16(
                        wf[cf], hf[ch], acc[ch][cf], 0, 0, 0);
        }

        __syncthreads();   // all reads of H done before overwrite

        // epilogue: lane holds pt = l15, neurons nb..nb+3 (4 consecutive)
        #pragma unroll
        for (int cf = 0; cf < 4; ++cf) {
            const int nb = (wave * 4 + cf) * 16 + g * 4;
            float4 bb4 = *(const float4*)(bs[L] + nb);
            float bb[4] = {bb4.x, bb4.y, bb4.z, bb4.w};
            short4v o0, o1, o2, o3, o4;
            #pragma unroll
            for (int r = 0; r < 4; ++r) {
                float z   = acc[0][cf][r] + bb[r];
                float a   = fast_tanh(z);
                float s   = 1.0f - a * a;
                float zgx = acc[1][cf][r];
                float zgy = acc[2][cf][r];
                float gx  = s * zgx;
                float gy  = s * zgy;
                float xx  = s * acc[3][cf][r] - 2.0f * a * gx * zgx;
                float yy  = s * acc[4][cf][r] - 2.0f * a * gy * zgy;
                o0[r] = f2bf(a);
                o1[r] = f2bf(gx);
                o2[r] = f2bf(gy);
                o3[r] = f2bf(xx);
                o4[r] = f2bf(yy);
            }
            const int kk = l15 * 256 + (nb ^ swzB);
            *(short4v*)&Hs[0 * 4096 + kk] = o0;
            *(short4v*)&Hs[1 * 4096 + kk] = o1;
            *(short4v*)&Hs[2 * 4096 + kk] = o2;
            *(short4v*)&Hs[3 * 4096 + kk] = o3;
            *(short4v*)&Hs[4 * 4096 + kk] = o4;
        }
    }

    __syncthreads();

    // ---------------- final layer 256 -> 1 + loss terms ----------------
    float r0 = 0.f, r1 = 0.f, r2 = 0.f, r3 = 0.f, r4 = 0.f;
    const float bias5 = b5[0];
    const int c0 = lane * 4;
    float4 w54 = *(const float4*)(W5 + c0);
    float w5[4] = {w54.x, w54.y, w54.z, w54.w};

    #pragma unroll
    for (int sub = 0; sub < 4; ++sub) {
        int pt  = 4 * wave + sub;
        int idx = pt * 256 + (c0 ^ ((pt & 7) << 3));
        short4v hv = *(const short4v*)&Hs[0 * 4096 + idx];
        short4v hx = *(const short4v*)&Hs[3 * 4096 + idx];
        short4v hy = *(const short4v*)&Hs[4 * 4096 + idx];
        float sT = 0.f, sR = 0.f;
        #pragma unroll
        for (int q = 0; q < 4; ++q) {
            sT += bf2f(hv[q]) * w5[q];
            sR += (bf2f(hx[q]) + bf2f(hy[q])) * w5[q];
        }
        #pragma unroll
        for (int off = 32; off > 0; off >>= 1) {
            sT += __shfl_down(sT, off, 64);
            sR += __shfl_down(sR, off, 64);
        }
        if (lane == 0) {
            float T = sT + bias5;
            r0 += sR * sR;
            int m = vals[pbase + pt];
            if (m == 1)      { float d = T - 1200.0f; r1 += d * d; r2 += 1.0f; }
            else if (m == 2) { float d = T - 25.0f;   r3 += d * d; r4 += 1.0f; }
        }
    }

    if (lane == 0) {
        red[wave][0] = r0; red[wave][1] = r1; red[wave][2] = r2;
        red[wave][3] = r3; red[wave][4] = r4;
    }
    __syncthreads();
    if (tid == 0) {
        #pragma unroll
        for (int c = 0; c < 5; ++c)
            partials[blockIdx.x * 5 + c] =
                red[0][c] + red[1][c] + red[2][c] + red[3][c];
    }
}

__global__ __launch_bounds__(256) void pinn_reduce(const float* __restrict__ p,
                                                   float* __restrict__ out)
{
    float s[5] = {0.f, 0.f, 0.f, 0.f, 0.f};
    for (int idx = threadIdx.x; idx < NBLK; idx += 256) {
        #pragma unroll
        for (int c = 0; c < 5; ++c) s[c] += p[idx * 5 + c];
    }
    #pragma unroll
    for (int c = 0; c < 5; ++c) {
        #pragma unroll
        for (int off = 32; off > 0; off >>= 1)
            s[c] += __shfl_down(s[c], off, 64);
    }
    __shared__ float r[4][5];
    int wave = threadIdx.x >> 6;
    int lane = threadIdx.x & 63;
    if (lane == 0) {
        #pragma unroll
        for (int c = 0; c < 5; ++c) r[wave][c] = s[c];
    }
    __syncthreads();
    if (threadIdx.x == 0) {
        float t[5];
        #pragma unroll
        for (int c = 0; c < 5; ++c) t[c] = r[0][c] + r[1][c] + r[2][c] + r[3][c];
        out[0] = t[0] / (float)N_PTS
               + t[1] / fmaxf(t[2], 1.0f)
               + t[3] / fmaxf(t[4], 1.0f);
    }
}

extern "C" void kernel_launch(void* const* d_in, const int* in_sizes, int n_in,
                              void* d_out, int out_size, void* d_ws, size_t ws_size,
                              hipStream_t stream) {
    const float* vect = (const float*)d_in[0];
    const int*   vals = (const int*)d_in[1];
    const float* W0 = (const float*)d_in[2];
    const float* b0 = (const float*)d_in[3];
    const float* W1 = (const float*)d_in[4];
    const float* b1 = (const float*)d_in[5];
    const float* W2 = (const float*)d_in[6];
    const float* b2 = (const float*)d_in[7];
    const float* W3 = (const float*)d_in[8];
    const float* b3 = (const float*)d_in[9];
    const float* W4 = (const float*)d_in[10];
    const float* b4 = (const float*)d_in[11];
    const float* W5 = (const float*)d_in[12];
    const float* b5 = (const float*)d_in[13];

    float* partials = (float*)d_ws;                        // 4096*5*4 = 80 KB
    short* Wt       = (short*)((char*)d_ws + 131072);      // 4*256*256*2 = 512 KB
    float* out      = (float*)d_out;

    conv_w<<<1024, 256, 0, stream>>>(W1, W2, W3, W4, Wt);
    pinn_main<<<NBLK, 256, 0, stream>>>(vect, vals, W0, b0, b1, b2, b3, b4,
                                        W5, b5, Wt, partials);
    pinn_reduce<<<1, 256, 0, stream>>>(partials, out);
}

// Round 4
// 289.101 us; speedup vs baseline: 1.0365x; 1.0365x over previous
//
#include <hip/hip_runtime.h>
#include <hip/hip_bf16.h>

#define N_PTS   65536
#define PBLK    16                 // points per block
#define NBLK    (N_PTS / PBLK)     // 4096 blocks
#define HID     256
#define NCH     4                  // v, p=gx+gy, m=gx-gy, h=hxx+hyy

typedef __attribute__((ext_vector_type(8))) short short8;   // 8 bf16 = 4 VGPR
typedef __attribute__((ext_vector_type(4))) short short4v;  // 4 bf16 = 8 B
typedef __attribute__((ext_vector_type(4))) float floatx4;  // MFMA C/D

__device__ __forceinline__ short f2bf(float x) {
    union { __hip_bfloat16 b; short s; } u;
    u.b = __float2bfloat16(x);
    return u.s;
}
__device__ __forceinline__ float bf2f(short h) {
    union { unsigned u; float f; } v;
    v.u = ((unsigned)(unsigned short)h) << 16;
    return v.f;
}
__device__ __forceinline__ float fast_tanh(float x) {
    float e = __expf(2.0f * x);
    return 1.0f - 2.0f / (e + 1.0f);
}

// ---- weight transpose+convert: Wt[L][n][k] = bf16(W_L[k][n]) ----
__global__ __launch_bounds__(256) void conv_w(
    const float* __restrict__ W1, const float* __restrict__ W2,
    const float* __restrict__ W3, const float* __restrict__ W4,
    short* __restrict__ Wt)
{
    int layer = blockIdx.x >> 8;
    int n     = blockIdx.x & 255;
    const float* W = (layer == 0) ? W1 : (layer == 1) ? W2 : (layer == 2) ? W3 : W4;
    int k = threadIdx.x;
    Wt[((layer << 8) + n) * 256 + k] = f2bf(W[k * 256 + n]);
}

__global__ __launch_bounds__(512, 4) void pinn_main(
    const float* __restrict__ vect, const int* __restrict__ vals,
    const float* __restrict__ W0, const float* __restrict__ b0,
    const float* __restrict__ b1, const float* __restrict__ b2,
    const float* __restrict__ b3, const float* __restrict__ b4,
    const float* __restrict__ W5, const float* __restrict__ b5,
    const short* __restrict__ Wt, float* __restrict__ partials)
{
    // H[ch][pt][k] bf16, swizzled: elem = ch*4096 + pt*256 + (k ^ ((pt&7)<<3))
    __shared__ __align__(16) short Hs[NCH * PBLK * HID];   // 32 KB
    __shared__ float red[8][5];

    const int tid   = threadIdx.x;
    const int wave  = tid >> 6;
    const int lane  = tid & 63;
    const int g     = lane >> 4;          // lane group 0..3
    const int l15   = lane & 15;
    const int pbase = blockIdx.x * PBLK;
    const int swzB  = (l15 & 7) << 3;

    // ---------------- layer 0: 2 -> 256 (fp32 VALU) ----------------
    {
        const int pt = tid >> 5;                 // 0..15
        const int c0 = (tid & 31) * 8;           // 8 neurons per thread
        float4 wxa = *(const float4*)(W0 + c0);
        float4 wxb = *(const float4*)(W0 + c0 + 4);
        float4 wya = *(const float4*)(W0 + HID + c0);
        float4 wyb = *(const float4*)(W0 + HID + c0 + 4);
        float4 bba = *(const float4*)(b0 + c0);
        float4 bbb = *(const float4*)(b0 + c0 + 4);
        float wx[8] = {wxa.x, wxa.y, wxa.z, wxa.w, wxb.x, wxb.y, wxb.z, wxb.w};
        float wy[8] = {wya.x, wya.y, wya.z, wya.w, wyb.x, wyb.y, wyb.z, wyb.w};
        float bb[8] = {bba.x, bba.y, bba.z, bba.w, bbb.x, bbb.y, bbb.z, bbb.w};
        float x = vect[(pbase + pt) * 2 + 0];
        float y = vect[(pbase + pt) * 2 + 1];
        short8 ov, op, om, oh;
        #pragma unroll
        for (int q = 0; q < 8; ++q) {
            float z  = x * wx[q] + y * wy[q] + bb[q];
            float a  = fast_tanh(z);
            float s  = 1.0f - a * a;
            float gx = s * wx[q];
            float gy = s * wy[q];
            ov[q] = f2bf(a);
            op[q] = f2bf(gx + gy);
            om[q] = f2bf(gx - gy);
            oh[q] = f2bf(-2.0f * a * (gx * wx[q] + gy * wy[q]));
        }
        int idx = pt * 256 + (c0 ^ ((pt & 7) << 3));
        *(short8*)&Hs[0 * 4096 + idx] = ov;
        *(short8*)&Hs[1 * 4096 + idx] = op;
        *(short8*)&Hs[2 * 4096 + idx] = om;
        *(short8*)&Hs[3 * 4096 + idx] = oh;
    }

    // ---------------- hidden layers 1..4 via MFMA (D = W_tile * H^T) ----------------
    const float* bs[4] = {b1, b2, b3, b4};

    #pragma unroll
    for (int L = 0; L < 4; ++L) {
        floatx4 acc[NCH][2];
        #pragma unroll
        for (int ch = 0; ch < NCH; ++ch)
            #pragma unroll
            for (int cf = 0; cf < 2; ++cf)
                acc[ch][cf] = (floatx4){0.f, 0.f, 0.f, 0.f};

        // A-frag (W rows): wave owns neurons [wave*32, wave*32+32)
        const short* wp0 = Wt + L * 65536 + (wave * 32 + l15) * 256 + g * 8;
        const short* wp1 = wp0 + 16 * 256;

        __syncthreads();   // H writes from previous stage visible

        #pragma unroll
        for (int ks = 0; ks < 8; ++ks) {
            const int ko = (g * 8 + ks * 32) ^ swzB;
            short8 hf[NCH];
            #pragma unroll
            for (int ch = 0; ch < NCH; ++ch)
                hf[ch] = *(const short8*)&Hs[ch * 4096 + l15 * 256 + ko];
            short8 wf0 = *(const short8*)(wp0 + ks * 32);
            short8 wf1 = *(const short8*)(wp1 + ks * 32);
            #pragma unroll
            for (int ch = 0; ch < NCH; ++ch) {
                acc[ch][0] = __builtin_amdgcn_mfma_f32_16x16x32_bf16(
                    wf0, hf[ch], acc[ch][0], 0, 0, 0);
                acc[ch][1] = __builtin_amdgcn_mfma_f32_16x16x32_bf16(
                    wf1, hf[ch], acc[ch][1], 0, 0, 0);
            }
        }

        __syncthreads();   // all reads of H done before overwrite

        // epilogue: lane holds point l15, 4 consecutive neurons per cf
        #pragma unroll
        for (int cf = 0; cf < 2; ++cf) {
            const int nb = wave * 32 + cf * 16 + g * 4;
            float4 bb4 = *(const float4*)(bs[L] + nb);
            float bb[4] = {bb4.x, bb4.y, bb4.z, bb4.w};
            short4v o0, o1, o2, o3;
            #pragma unroll
            for (int r = 0; r < 4; ++r) {
                float z  = acc[0][cf][r] + bb[r];
                float a  = fast_tanh(z);
                float s  = 1.0f - a * a;
                float zp = acc[1][cf][r];
                float zm = acc[2][cf][r];
                float zh = acc[3][cf][r];
                o0[r] = f2bf(a);
                o1[r] = f2bf(s * zp);
                o2[r] = f2bf(s * zm);
                o3[r] = f2bf(s * zh - a * s * (zp * zp + zm * zm));
            }
            const int kk = l15 * 256 + (nb ^ swzB);
            *(short4v*)&Hs[0 * 4096 + kk] = o0;
            *(short4v*)&Hs[1 * 4096 + kk] = o1;
            *(short4v*)&Hs[2 * 4096 + kk] = o2;
            *(short4v*)&Hs[3 * 4096 + kk] = o3;
        }
    }

    __syncthreads();

    // ---------------- final layer 256 -> 1 + loss terms ----------------
    float r0 = 0.f, r1 = 0.f, r2 = 0.f, r3 = 0.f, r4 = 0.f;
    const float bias5 = b5[0];
    const int c0 = lane * 4;
    float4 w54 = *(const float4*)(W5 + c0);
    float w5[4] = {w54.x, w54.y, w54.z, w54.w};

    #pragma unroll
    for (int sub = 0; sub < 2; ++sub) {
        int pt  = wave * 2 + sub;
        int idx = pt * 256 + (c0 ^ ((pt & 7) << 3));
        short4v hv = *(const short4v*)&Hs[0 * 4096 + idx];
        short4v hh = *(const short4v*)&Hs[3 * 4096 + idx];
        float sT = 0.f, sR = 0.f;
        #pragma unroll
        for (int q = 0; q < 4; ++q) {
            sT += bf2f(hv[q]) * w5[q];
            sR += bf2f(hh[q]) * w5[q];
        }
        #pragma unroll
        for (int off = 32; off > 0; off >>= 1) {
            sT += __shfl_down(sT, off, 64);
            sR += __shfl_down(sR, off, 64);
        }
        if (lane == 0) {
            float T = sT + bias5;
            r0 += sR * sR;
            int m = vals[pbase + pt];
            if (m == 1)      { float d = T - 1200.0f; r1 += d * d; r2 += 1.0f; }
            else if (m == 2) { float d = T - 25.0f;   r3 += d * d; r4 += 1.0f; }
        }
    }

    if (lane == 0) {
        red[wave][0] = r0; red[wave][1] = r1; red[wave][2] = r2;
        red[wave][3] = r3; red[wave][4] = r4;
    }
    __syncthreads();
    if (tid == 0) {
        #pragma unroll
        for (int c = 0; c < 5; ++c) {
            float s = 0.f;
            #pragma unroll
            for (int w = 0; w < 8; ++w) s += red[w][c];
            partials[blockIdx.x * 5 + c] = s;
        }
    }
}

__global__ __launch_bounds__(256) void pinn_reduce(const float* __restrict__ p,
                                                   float* __restrict__ out)
{
    float s[5] = {0.f, 0.f, 0.f, 0.f, 0.f};
    for (int idx = threadIdx.x; idx < NBLK; idx += 256) {
        #pragma unroll
        for (int c = 0; c < 5; ++c) s[c] += p[idx * 5 + c];
    }
    #pragma unroll
    for (int c = 0; c < 5; ++c) {
        #pragma unroll
        for (int off = 32; off > 0; off >>= 1)
            s[c] += __shfl_down(s[c], off, 64);
    }
    __shared__ float r[4][5];
    int wave = threadIdx.x >> 6;
    int lane = threadIdx.x & 63;
    if (lane == 0) {
        #pragma unroll
        for (int c = 0; c < 5; ++c) r[wave][c] = s[c];
    }
    __syncthreads();
    if (threadIdx.x == 0) {
        float t[5];
        #pragma unroll
        for (int c = 0; c < 5; ++c) t[c] = r[0][c] + r[1][c] + r[2][c] + r[3][c];
        out[0] = t[0] / (float)N_PTS
               + t[1] / fmaxf(t[2], 1.0f)
               + t[3] / fmaxf(t[4], 1.0f);
    }
}

extern "C" void kernel_launch(void* const* d_in, const int* in_sizes, int n_in,
                              void* d_out, int out_size, void* d_ws, size_t ws_size,
                              hipStream_t stream) {
    const float* vect = (const float*)d_in[0];
    const int*   vals = (const int*)d_in[1];
    const float* W0 = (const float*)d_in[2];
    const float* b0 = (const float*)d_in[3];
    const float* W1 = (const float*)d_in[4];
    const float* b1 = (const float*)d_in[5];
    const float* W2 = (const float*)d_in[6];
    const float* b2 = (const float*)d_in[7];
    const float* W3 = (const float*)d_in[8];
    const float* b3 = (const float*)d_in[9];
    const float* W4 = (const float*)d_in[10];
    const float* b4 = (const float*)d_in[11];
    const float* W5 = (const float*)d_in[12];
    const float* b5 = (const float*)d_in[13];

    float* partials = (float*)d_ws;                        // 4096*5*4 = 80 KB
    short* Wt       = (short*)((char*)d_ws + 131072);      // 512 KB
    float* out      = (float*)d_out;

    conv_w<<<1024, 256, 0, stream>>>(W1, W2, W3, W4, Wt);
    pinn_main<<<NBLK, 512, 0, stream>>>(vect, vals, W0, b0, b1, b2, b3, b4,
                                        W5, b5, Wt, partials);
    pinn_reduce<<<1, 256, 0, stream>>>(partials, out);
}

// Round 5
// 189.158 us; speedup vs baseline: 1.5842x; 1.5284x over previous
//
#include <hip/hip_runtime.h>
#include <hip/hip_bf16.h>

#define N_PTS   65536
#define PBLK    32                 // points per block
#define NBLK    (N_PTS / PBLK)     // 2048 blocks
#define HID     256
#define NCH     4                  // v, p=gx+gy, m=gx-gy, h=hxx+hyy

typedef __attribute__((ext_vector_type(8)))  short short8;    // 8 bf16 = 4 VGPR
typedef __attribute__((ext_vector_type(4)))  short short4v;   // 4 bf16 = 8 B
typedef __attribute__((ext_vector_type(16))) float floatx16;  // 32x32 MFMA C/D

__device__ __forceinline__ short f2bf(float x) {
    union { __hip_bfloat16 b; short s; } u;
    u.b = __float2bfloat16(x);
    return u.s;
}
__device__ __forceinline__ float bf2f(short h) {
    union { unsigned u; float f; } v;
    v.u = ((unsigned)(unsigned short)h) << 16;
    return v.f;
}
__device__ __forceinline__ float fast_tanh(float x) {
    float e = __expf(2.0f * x);
    return 1.0f - 2.0f / (e + 1.0f);
}

// ---- weight transpose+convert: Wt[L][n][k] = bf16(W_L[k][n]) ----
__global__ __launch_bounds__(256) void conv_w(
    const float* __restrict__ W1, const float* __restrict__ W2,
    const float* __restrict__ W3, const float* __restrict__ W4,
    short* __restrict__ Wt)
{
    int layer = blockIdx.x >> 8;
    int n     = blockIdx.x & 255;
    const float* W = (layer == 0) ? W1 : (layer == 1) ? W2 : (layer == 2) ? W3 : W4;
    int k = threadIdx.x;
    Wt[((layer << 8) + n) * 256 + k] = f2bf(W[k * 256 + n]);
}

__global__ __launch_bounds__(256, 2) void pinn_main(
    const float* __restrict__ vect, const int* __restrict__ vals,
    const float* __restrict__ W0, const float* __restrict__ b0,
    const float* __restrict__ b1, const float* __restrict__ b2,
    const float* __restrict__ b3, const float* __restrict__ b4,
    const float* __restrict__ W5, const float* __restrict__ b5,
    const short* __restrict__ Wt, float* __restrict__ partials)
{
    // H[ch][pt][k] bf16: elem = ch*8192 + pt*256 + (k ^ ((pt&15)<<3))   (64 KB)
    __shared__ __align__(16) short Hs[NCH * PBLK * HID];
    __shared__ float red[4][5];

    const int tid   = threadIdx.x;
    const int wave  = tid >> 6;
    const int lane  = tid & 63;
    const int pt    = lane & 31;          // MFMA column = point
    const int hi    = lane >> 5;
    const int pbase = blockIdx.x * PBLK;
    const int swz   = (pt & 15) << 3;

    // ---------------- layer 0: 2 -> 256 (fp32 VALU) ----------------
    {
        const int p0 = tid & 31;          // point
        const int c0 = (tid >> 5) * 32;   // 32 neurons per thread
        const int sz = (p0 & 15) << 3;
        float x = vect[(pbase + p0) * 2 + 0];
        float y = vect[(pbase + p0) * 2 + 1];
        #pragma unroll
        for (int jj = 0; jj < 4; ++jj) {
            const int cb = c0 + jj * 8;
            float4 wxa = *(const float4*)(W0 + cb);
            float4 wxb = *(const float4*)(W0 + cb + 4);
            float4 wya = *(const float4*)(W0 + HID + cb);
            float4 wyb = *(const float4*)(W0 + HID + cb + 4);
            float4 bba = *(const float4*)(b0 + cb);
            float4 bbb = *(const float4*)(b0 + cb + 4);
            float wx[8] = {wxa.x, wxa.y, wxa.z, wxa.w, wxb.x, wxb.y, wxb.z, wxb.w};
            float wy[8] = {wya.x, wya.y, wya.z, wya.w, wyb.x, wyb.y, wyb.z, wyb.w};
            float bb[8] = {bba.x, bba.y, bba.z, bba.w, bbb.x, bbb.y, bbb.z, bbb.w};
            short8 ov, op, om, oh;
            #pragma unroll
            for (int q = 0; q < 8; ++q) {
                float z  = x * wx[q] + y * wy[q] + bb[q];
                float a  = fast_tanh(z);
                float s  = 1.0f - a * a;
                float gx = s * wx[q];
                float gy = s * wy[q];
                ov[q] = f2bf(a);
                op[q] = f2bf(gx + gy);
                om[q] = f2bf(gx - gy);
                oh[q] = f2bf(-2.0f * a * (gx * wx[q] + gy * wy[q]));
            }
            const int idx = p0 * 256 + (cb ^ sz);
            *(short8*)&Hs[0 * 8192 + idx] = ov;
            *(short8*)&Hs[1 * 8192 + idx] = op;
            *(short8*)&Hs[2 * 8192 + idx] = om;
            *(short8*)&Hs[3 * 8192 + idx] = oh;
        }
    }

    // ---------------- hidden layers 1..4: 32x32x16 MFMA (D = W * H^T) ----------------
    const float* bs[4] = {b1, b2, b3, b4};

    #pragma unroll
    for (int L = 0; L < 4; ++L) {
        floatx16 acc[2][NCH];
        #pragma unroll
        for (int t = 0; t < 2; ++t)
            #pragma unroll
            for (int ch = 0; ch < NCH; ++ch)
                acc[t][ch] = (floatx16)(0.0f);

        // A-frag: row = wave*64 + t*32 + pt(lane&31), k = ks*16 + hi*8 + j
        const short* wbase = Wt + L * 65536 + (wave * 64 + pt) * 256 + hi * 8;

        __syncthreads();   // H writes visible

        #pragma unroll
        for (int ks = 0; ks < 16; ++ks) {
            const int kb = ks * 16 + hi * 8;           // unswizzled k base
            const int ko = kb ^ swz;
            short8 bf[NCH];
            #pragma unroll
            for (int ch = 0; ch < NCH; ++ch)
                bf[ch] = *(const short8*)&Hs[ch * 8192 + pt * 256 + ko];
            short8 af0 = *(const short8*)(wbase + 0 * 8192 + ks * 16);
            short8 af1 = *(const short8*)(wbase + 32 * 256 + ks * 16);
            #pragma unroll
            for (int ch = 0; ch < NCH; ++ch) {
                acc[0][ch] = __builtin_amdgcn_mfma_f32_32x32x16_bf16(
                    af0, bf[ch], acc[0][ch], 0, 0, 0);
                acc[1][ch] = __builtin_amdgcn_mfma_f32_32x32x16_bf16(
                    af1, bf[ch], acc[1][ch], 0, 0, 0);
            }
        }

        __syncthreads();   // H reads done before overwrite

        // epilogue: lane holds point pt; reg r of quad q -> neuron nq + r
        #pragma unroll
        for (int t = 0; t < 2; ++t) {
            #pragma unroll
            for (int q = 0; q < 4; ++q) {
                const int nq = wave * 64 + t * 32 + q * 8 + hi * 4;
                float4 bb4 = *(const float4*)(bs[L] + nq);
                float bb[4] = {bb4.x, bb4.y, bb4.z, bb4.w};
                short4v o0, o1, o2, o3;
                #pragma unroll
                for (int r = 0; r < 4; ++r) {
                    const int reg = q * 4 + r;
                    float z  = acc[t][0][reg] + bb[r];
                    float a  = fast_tanh(z);
                    float s  = 1.0f - a * a;
                    float zp = acc[t][1][reg];
                    float zm = acc[t][2][reg];
                    float zh = acc[t][3][reg];
                    o0[r] = f2bf(a);
                    o1[r] = f2bf(s * zp);
                    o2[r] = f2bf(s * zm);
                    o3[r] = f2bf(s * zh - a * s * (zp * zp + zm * zm));
                }
                const int kk = pt * 256 + (nq ^ swz);
                *(short4v*)&Hs[0 * 8192 + kk] = o0;
                *(short4v*)&Hs[1 * 8192 + kk] = o1;
                *(short4v*)&Hs[2 * 8192 + kk] = o2;
                *(short4v*)&Hs[3 * 8192 + kk] = o3;
            }
        }
    }

    __syncthreads();

    // ---------------- final layer 256 -> 1 + loss terms ----------------
    // lane group of 8 shares point fp = wave*8 + (lane>>3); each lane sums 32 k's
    const int fp  = wave * 8 + (lane >> 3);
    const int kc  = (lane & 7) * 32;
    const int fsz = (fp & 15) << 3;
    float sT = 0.f, sR = 0.f;
    #pragma unroll
    for (int j = 0; j < 4; ++j) {
        const int kb = kc + j * 8;
        const int ke = fp * 256 + (kb ^ fsz);
        short8 hv = *(const short8*)&Hs[0 * 8192 + ke];
        short8 hh = *(const short8*)&Hs[3 * 8192 + ke];
        float4 w5a = *(const float4*)(W5 + kb);
        float4 w5b = *(const float4*)(W5 + kb + 4);
        float w5[8] = {w5a.x, w5a.y, w5a.z, w5a.w, w5b.x, w5b.y, w5b.z, w5b.w};
        #pragma unroll
        for (int i = 0; i < 8; ++i) {
            sT += bf2f(hv[i]) * w5[i];
            sR += bf2f(hh[i]) * w5[i];
        }
    }
    // reduce across the 8 lanes sharing fp
    sT += __shfl_down(sT, 4, 64); sR += __shfl_down(sR, 4, 64);
    sT += __shfl_down(sT, 2, 64); sR += __shfl_down(sR, 2, 64);
    sT += __shfl_down(sT, 1, 64); sR += __shfl_down(sR, 1, 64);

    float r0 = 0.f, r1 = 0.f, r2 = 0.f, r3 = 0.f, r4 = 0.f;
    if ((lane & 7) == 0) {
        float T = sT + b5[0];
        r0 = sR * sR;
        int m = vals[pbase + fp];
        if (m == 1)      { float d = T - 1200.0f; r1 = d * d; r2 = 1.0f; }
        else if (m == 2) { float d = T - 25.0f;   r3 = d * d; r4 = 1.0f; }
    }
    // reduce the 8 group leaders (lanes 0,8,...,56)
    #pragma unroll
    for (int off = 32; off >= 8; off >>= 1) {
        r0 += __shfl_down(r0, off, 64);
        r1 += __shfl_down(r1, off, 64);
        r2 += __shfl_down(r2, off, 64);
        r3 += __shfl_down(r3, off, 64);
        r4 += __shfl_down(r4, off, 64);
    }
    if (lane == 0) {
        red[wave][0] = r0; red[wave][1] = r1; red[wave][2] = r2;
        red[wave][3] = r3; red[wave][4] = r4;
    }
    __syncthreads();
    if (tid == 0) {
        #pragma unroll
        for (int c = 0; c < 5; ++c)
            partials[blockIdx.x * 5 + c] =
                red[0][c] + red[1][c] + red[2][c] + red[3][c];
    }
}

__global__ __launch_bounds__(256) void pinn_reduce(const float* __restrict__ p,
                                                   float* __restrict__ out)
{
    float s[5] = {0.f, 0.f, 0.f, 0.f, 0.f};
    for (int idx = threadIdx.x; idx < NBLK; idx += 256) {
        #pragma unroll
        for (int c = 0; c < 5; ++c) s[c] += p[idx * 5 + c];
    }
    #pragma unroll
    for (int c = 0; c < 5; ++c) {
        #pragma unroll
        for (int off = 32; off > 0; off >>= 1)
            s[c] += __shfl_down(s[c], off, 64);
    }
    __shared__ float r[4][5];
    int wave = threadIdx.x >> 6;
    int lane = threadIdx.x & 63;
    if (lane == 0) {
        #pragma unroll
        for (int c = 0; c < 5; ++c) r[wave][c] = s[c];
    }
    __syncthreads();
    if (threadIdx.x == 0) {
        float t[5];
        #pragma unroll
        for (int c = 0; c < 5; ++c) t[c] = r[0][c] + r[1][c] + r[2][c] + r[3][c];
        out[0] = t[0] / (float)N_PTS
               + t[1] / fmaxf(t[2], 1.0f)
               + t[3] / fmaxf(t[4], 1.0f);
    }
}

extern "C" void kernel_launch(void* const* d_in, const int* in_sizes, int n_in,
                              void* d_out, int out_size, void* d_ws, size_t ws_size,
                              hipStream_t stream) {
    const float* vect = (const float*)d_in[0];
    const int*   vals = (const int*)d_in[1];
    const float* W0 = (const float*)d_in[2];
    const float* b0 = (const float*)d_in[3];
    const float* W1 = (const float*)d_in[4];
    const float* b1 = (const float*)d_in[5];
    const float* W2 = (const float*)d_in[6];
    const float* b2 = (const float*)d_in[7];
    const float* W3 = (const float*)d_in[8];
    const float* b3 = (const float*)d_in[9];
    const float* W4 = (const float*)d_in[10];
    const float* b4 = (const float*)d_in[11];
    const float* W5 = (const float*)d_in[12];
    const float* b5 = (const float*)d_in[13];

    float* partials = (float*)d_ws;                        // 2048*5*4 = 40 KB
    short* Wt       = (short*)((char*)d_ws + 131072);      // 512 KB
    float* out      = (float*)d_out;

    conv_w<<<1024, 256, 0, stream>>>(W1, W2, W3, W4, Wt);
    pinn_main<<<NBLK, 256, 0, stream>>>(vect, vals, W0, b0, b1, b2, b3, b4,
                                        W5, b5, Wt, partials);
    pinn_reduce<<<1, 256, 0, stream>>>(partials, out);
}

// Round 6
// 186.547 us; speedup vs baseline: 1.6064x; 1.0140x over previous
//
#include <hip/hip_runtime.h>
#include <hip/hip_bf16.h>

#define N_PTS   65536
#define PBLK    32                 // points per block
#define NBLK    (N_PTS / PBLK)     // 2048 blocks
#define HID     256
#define NCH     4                  // v, p=gx+gy, m=gx-gy, h=hxx+hyy

typedef __attribute__((ext_vector_type(8)))  short short8;    // 8 bf16 = 4 VGPR
typedef __attribute__((ext_vector_type(16))) float floatx16;  // 32x32 MFMA C/D
typedef __attribute__((ext_vector_type(2)))  unsigned uint2v;
typedef __attribute__((ext_vector_type(4)))  unsigned uint4v;

__device__ __forceinline__ short f2bf(float x) {
    union { __hip_bfloat16 b; short s; } u;
    u.b = __float2bfloat16(x);
    return u.s;
}
__device__ __forceinline__ float bf2f(short h) {
    union { unsigned u; float f; } v;
    v.u = ((unsigned)(unsigned short)h) << 16;
    return v.f;
}
// pack two f32 -> two bf16 (truncating) in ONE v_perm_b32
__device__ __forceinline__ unsigned pk2(float lo, float hi) {
    union { float f; unsigned u; } a, b;
    a.f = lo; b.f = hi;
    return __builtin_amdgcn_perm(b.u, a.u, 0x07060302u);
}
__device__ __forceinline__ float fast_tanh(float x) {
    float e = __expf(2.0f * x);
    return 1.0f - 2.0f / (e + 1.0f);
}

// ---- weight transpose+convert: Wt[L][n][k] = bf16(W_L[k][n]) ----
__global__ __launch_bounds__(256) void conv_w(
    const float* __restrict__ W1, const float* __restrict__ W2,
    const float* __restrict__ W3, const float* __restrict__ W4,
    short* __restrict__ Wt)
{
    int layer = blockIdx.x >> 8;
    int n     = blockIdx.x & 255;
    const float* W = (layer == 0) ? W1 : (layer == 1) ? W2 : (layer == 2) ? W3 : W4;
    int k = threadIdx.x;
    Wt[((layer << 8) + n) * 256 + k] = f2bf(W[k * 256 + n]);
}

__global__ __launch_bounds__(512, 4) void pinn_main(
    const float* __restrict__ vect, const int* __restrict__ vals,
    const float* __restrict__ W0, const float* __restrict__ b0,
    const float* __restrict__ b1, const float* __restrict__ b2,
    const float* __restrict__ b3, const float* __restrict__ b4,
    const float* __restrict__ W5, const float* __restrict__ b5,
    const short* __restrict__ Wt, float* __restrict__ partials)
{
    // H[ch][pt][k] bf16: elem = ch*8192 + pt*256 + (k ^ ((pt&15)<<3))   (64 KB)
    __shared__ __align__(16) short Hs[NCH * PBLK * HID];
    __shared__ float red[8][5];

    const int tid   = threadIdx.x;
    const int wave  = tid >> 6;
    const int lane  = tid & 63;
    const int pt    = lane & 31;          // MFMA column = point / A row
    const int hi    = lane >> 5;
    const int pbase = blockIdx.x * PBLK;
    const int swz   = (pt & 15) << 3;

    // ---------------- layer 0: 2 -> 256 (fp32 VALU) ----------------
    {
        const int p0 = tid & 31;          // point
        const int c0 = (tid >> 5) * 16;   // 16 neurons per thread
        const int sz = (p0 & 15) << 3;
        float x = vect[(pbase + p0) * 2 + 0];
        float y = vect[(pbase + p0) * 2 + 1];
        #pragma unroll
        for (int jj = 0; jj < 2; ++jj) {
            const int cb = c0 + jj * 8;
            float4 wxa = *(const float4*)(W0 + cb);
            float4 wxb = *(const float4*)(W0 + cb + 4);
            float4 wya = *(const float4*)(W0 + HID + cb);
            float4 wyb = *(const float4*)(W0 + HID + cb + 4);
            float4 bba = *(const float4*)(b0 + cb);
            float4 bbb = *(const float4*)(b0 + cb + 4);
            float wx[8] = {wxa.x, wxa.y, wxa.z, wxa.w, wxb.x, wxb.y, wxb.z, wxb.w};
            float wy[8] = {wya.x, wya.y, wya.z, wya.w, wyb.x, wyb.y, wyb.z, wyb.w};
            float bb[8] = {bba.x, bba.y, bba.z, bba.w, bbb.x, bbb.y, bbb.z, bbb.w};
            float av[8], pv[8], mv[8], hv[8];
            #pragma unroll
            for (int q = 0; q < 8; ++q) {
                float z  = x * wx[q] + y * wy[q] + bb[q];
                float a  = fast_tanh(z);
                float s  = 1.0f - a * a;
                float gx = s * wx[q];
                float gy = s * wy[q];
                av[q] = a;
                pv[q] = gx + gy;
                mv[q] = gx - gy;
                hv[q] = -2.0f * a * (gx * wx[q] + gy * wy[q]);
            }
            const int idx = p0 * 256 + (cb ^ sz);
            *(uint4v*)&Hs[0 * 8192 + idx] =
                (uint4v){pk2(av[0],av[1]), pk2(av[2],av[3]), pk2(av[4],av[5]), pk2(av[6],av[7])};
            *(uint4v*)&Hs[1 * 8192 + idx] =
                (uint4v){pk2(pv[0],pv[1]), pk2(pv[2],pv[3]), pk2(pv[4],pv[5]), pk2(pv[6],pv[7])};
            *(uint4v*)&Hs[2 * 8192 + idx] =
                (uint4v){pk2(mv[0],mv[1]), pk2(mv[2],mv[3]), pk2(mv[4],mv[5]), pk2(mv[6],mv[7])};
            *(uint4v*)&Hs[3 * 8192 + idx] =
                (uint4v){pk2(hv[0],hv[1]), pk2(hv[2],hv[3]), pk2(hv[4],hv[5]), pk2(hv[6],hv[7])};
        }
    }

    // ---------------- hidden layers 1..4: 32x32x16 MFMA (D = W * H^T) ----------------
    // wave owns 32 neurons (1 tile): rows wave*32 .. wave*32+31
    const float* bs[4] = {b1, b2, b3, b4};

    #pragma unroll
    for (int L = 0; L < 4; ++L) {
        floatx16 acc[NCH];
        #pragma unroll
        for (int ch = 0; ch < NCH; ++ch)
            acc[ch] = (floatx16)(0.0f);

        // A-frag: row = wave*32 + pt, k = ks*16 + hi*8 + j
        const short* wbase = Wt + L * 65536 + (wave * 32 + pt) * 256 + hi * 8;

        __syncthreads();   // H writes visible

        #pragma unroll
        for (int ks = 0; ks < 16; ++ks) {
            const int ko = (ks * 16 + hi * 8) ^ swz;
            short8 af = *(const short8*)(wbase + ks * 16);
            short8 bf[NCH];
            #pragma unroll
            for (int ch = 0; ch < NCH; ++ch)
                bf[ch] = *(const short8*)&Hs[ch * 8192 + pt * 256 + ko];
            #pragma unroll
            for (int ch = 0; ch < NCH; ++ch)
                acc[ch] = __builtin_amdgcn_mfma_f32_32x32x16_bf16(
                    af, bf[ch], acc[ch], 0, 0, 0);
        }

        __syncthreads();   // H reads done before overwrite

        // epilogue: lane holds point pt; reg q*4+r -> neuron wave*32 + q*8 + hi*4 + r
        #pragma unroll
        for (int q = 0; q < 4; ++q) {
            const int nq = wave * 32 + q * 8 + hi * 4;
            float4 bb4 = *(const float4*)(bs[L] + nq);
            float bb[4] = {bb4.x, bb4.y, bb4.z, bb4.w};
            float av[4], pv[4], mv[4], hv[4];
            #pragma unroll
            for (int r = 0; r < 4; ++r) {
                const int reg = q * 4 + r;
                float z  = acc[0][reg] + bb[r];
                float a  = fast_tanh(z);
                float s  = 1.0f - a * a;
                float zp = acc[1][reg];
                float zm = acc[2][reg];
                float zh = acc[3][reg];
                av[r] = a;
                pv[r] = s * zp;
                mv[r] = s * zm;
                hv[r] = s * zh - a * s * (zp * zp + zm * zm);
            }
            const int kk = pt * 256 + (nq ^ swz);
            *(uint2v*)&Hs[0 * 8192 + kk] = (uint2v){pk2(av[0],av[1]), pk2(av[2],av[3])};
            *(uint2v*)&Hs[1 * 8192 + kk] = (uint2v){pk2(pv[0],pv[1]), pk2(pv[2],pv[3])};
            *(uint2v*)&Hs[2 * 8192 + kk] = (uint2v){pk2(mv[0],mv[1]), pk2(mv[2],mv[3])};
            *(uint2v*)&Hs[3 * 8192 + kk] = (uint2v){pk2(hv[0],hv[1]), pk2(hv[2],hv[3])};
        }
    }

    __syncthreads();

    // ---------------- final layer 256 -> 1 + loss terms ----------------
    // 16 lanes share point fp = wave*4 + (lane>>4); each lane sums 16 k's
    const int fp  = wave * 4 + (lane >> 4);
    const int kc  = (lane & 15) * 16;
    const int fsz = (fp & 15) << 3;
    float sT = 0.f, sR = 0.f;
    #pragma unroll
    for (int j = 0; j < 2; ++j) {
        const int kb = kc + j * 8;
        const int ke = fp * 256 + (kb ^ fsz);
        short8 hv = *(const short8*)&Hs[0 * 8192 + ke];
        short8 hh = *(const short8*)&Hs[3 * 8192 + ke];
        float4 w5a = *(const float4*)(W5 + kb);
        float4 w5b = *(const float4*)(W5 + kb + 4);
        float w5[8] = {w5a.x, w5a.y, w5a.z, w5a.w, w5b.x, w5b.y, w5b.z, w5b.w};
        #pragma unroll
        for (int i = 0; i < 8; ++i) {
            sT += bf2f(hv[i]) * w5[i];
            sR += bf2f(hh[i]) * w5[i];
        }
    }
    // reduce across the 16 lanes sharing fp
    sT += __shfl_down(sT, 8, 64); sR += __shfl_down(sR, 8, 64);
    sT += __shfl_down(sT, 4, 64); sR += __shfl_down(sR, 4, 64);
    sT += __shfl_down(sT, 2, 64); sR += __shfl_down(sR, 2, 64);
    sT += __shfl_down(sT, 1, 64); sR += __shfl_down(sR, 1, 64);

    float r0 = 0.f, r1 = 0.f, r2 = 0.f, r3 = 0.f, r4 = 0.f;
    if ((lane & 15) == 0) {
        float T = sT + b5[0];
        r0 = sR * sR;
        int m = vals[pbase + fp];
        if (m == 1)      { float d = T - 1200.0f; r1 = d * d; r2 = 1.0f; }
        else if (m == 2) { float d = T - 25.0f;   r3 = d * d; r4 = 1.0f; }
    }
    // reduce the 4 group leaders (lanes 0,16,32,48)
    #pragma unroll
    for (int off = 32; off >= 16; off >>= 1) {
        r0 += __shfl_down(r0, off, 64);
        r1 += __shfl_down(r1, off, 64);
        r2 += __shfl_down(r2, off, 64);
        r3 += __shfl_down(r3, off, 64);
        r4 += __shfl_down(r4, off, 64);
    }
    if (lane == 0) {
        red[wave][0] = r0; red[wave][1] = r1; red[wave][2] = r2;
        red[wave][3] = r3; red[wave][4] = r4;
    }
    __syncthreads();
    if (tid == 0) {
        #pragma unroll
        for (int c = 0; c < 5; ++c) {
            float s = 0.f;
            #pragma unroll
            for (int w = 0; w < 8; ++w) s += red[w][c];
            partials[blockIdx.x * 5 + c] = s;
        }
    }
}

__global__ __launch_bounds__(256) void pinn_reduce(const float* __restrict__ p,
                                                   float* __restrict__ out)
{
    float s[5] = {0.f, 0.f, 0.f, 0.f, 0.f};
    for (int idx = threadIdx.x; idx < NBLK; idx += 256) {
        #pragma unroll
        for (int c = 0; c < 5; ++c) s[c] += p[idx * 5 + c];
    }
    #pragma unroll
    for (int c = 0; c < 5; ++c) {
        #pragma unroll
        for (int off = 32; off > 0; off >>= 1)
            s[c] += __shfl_down(s[c], off, 64);
    }
    __shared__ float r[4][5];
    int wave = threadIdx.x >> 6;
    int lane = threadIdx.x & 63;
    if (lane == 0) {
        #pragma unroll
        for (int c = 0; c < 5; ++c) r[wave][c] = s[c];
    }
    __syncthreads();
    if (threadIdx.x == 0) {
        float t[5];
        #pragma unroll
        for (int c = 0; c < 5; ++c) t[c] = r[0][c] + r[1][c] + r[2][c] + r[3][c];
        out[0] = t[0] / (float)N_PTS
               + t[1] / fmaxf(t[2], 1.0f)
               + t[3] / fmaxf(t[4], 1.0f);
    }
}

extern "C" void kernel_launch(void* const* d_in, const int* in_sizes, int n_in,
                              void* d_out, int out_size, void* d_ws, size_t ws_size,
                              hipStream_t stream) {
    const float* vect = (const float*)d_in[0];
    const int*   vals = (const int*)d_in[1];
    const float* W0 = (const float*)d_in[2];
    const float* b0 = (const float*)d_in[3];
    const float* W1 = (const float*)d_in[4];
    const float* b1 = (const float*)d_in[5];
    const float* W2 = (const float*)d_in[6];
    const float* b2 = (const float*)d_in[7];
    const float* W3 = (const float*)d_in[8];
    const float* b3 = (const float*)d_in[9];
    const float* W4 = (const float*)d_in[10];
    const float* b4 = (const float*)d_in[11];
    const float* W5 = (const float*)d_in[12];
    const float* b5 = (const float*)d_in[13];

    float* partials = (float*)d_ws;                        // 2048*5*4 = 40 KB
    short* Wt       = (short*)((char*)d_ws + 131072);      // 512 KB
    float* out      = (float*)d_out;

    conv_w<<<1024, 256, 0, stream>>>(W1, W2, W3, W4, Wt);
    pinn_main<<<NBLK, 512, 0, stream>>>(vect, vals, W0, b0, b1, b2, b3, b4,
                                        W5, b5, Wt, partials);
    pinn_reduce<<<1, 256, 0, stream>>>(partials, out);
}

// Round 7
// 169.896 us; speedup vs baseline: 1.7638x; 1.0980x over previous
//
#include <hip/hip_runtime.h>

#define N_PTS   65536
#define PBLK    32                 // points per block
#define NBLK    (N_PTS / PBLK)     // 2048 blocks
#define HID     256
#define NCH     4                  // v, p=gx+gy, m=gx-gy, h=hxx+hyy

typedef __attribute__((ext_vector_type(16))) float floatx16;  // 32x32 MFMA C/D
typedef __attribute__((ext_vector_type(2)))  unsigned uint2v;

__device__ __forceinline__ float fast_tanh(float x) {
    float e = __expf(2.0f * x);
    return 1.0f - 2.0f / (e + 1.0f);
}
// pack 4 f32 -> 4 fp8(e4m3) in one 32-bit word (2 cvt_pk instrs)
__device__ __forceinline__ unsigned pk4_fp8(float a, float b, float c, float d) {
    unsigned w = __builtin_amdgcn_cvt_pk_fp8_f32(a, b, 0, false);
    w = __builtin_amdgcn_cvt_pk_fp8_f32(c, d, (int)w, true);
    return w;
}

// ---- weight transpose+convert: Wt[L][n][k] = fp8(W_L[k][n]) ----
__global__ __launch_bounds__(64) void conv_w(
    const float* __restrict__ W1, const float* __restrict__ W2,
    const float* __restrict__ W3, const float* __restrict__ W4,
    unsigned char* __restrict__ Wt)
{
    int layer = blockIdx.x >> 8;
    int n     = blockIdx.x & 255;
    const float* W = (layer == 0) ? W1 : (layer == 1) ? W2 : (layer == 2) ? W3 : W4;
    int t = threadIdx.x;                      // word index: k = 4t..4t+3
    float a = W[(t * 4 + 0) * 256 + n];
    float b = W[(t * 4 + 1) * 256 + n];
    float c = W[(t * 4 + 2) * 256 + n];
    float d = W[(t * 4 + 3) * 256 + n];
    ((unsigned*)Wt)[((layer << 8) + n) * 64 + t] = pk4_fp8(a, b, c, d);
}

__global__ __launch_bounds__(512, 4) void pinn_main(
    const float* __restrict__ vect, const int* __restrict__ vals,
    const float* __restrict__ W0, const float* __restrict__ b0,
    const float* __restrict__ b1, const float* __restrict__ b2,
    const float* __restrict__ b3, const float* __restrict__ b4,
    const float* __restrict__ W5, const float* __restrict__ b5,
    const unsigned char* __restrict__ Wt, float* __restrict__ partials)
{
    // Hs[buf][ch][pt][k] fp8: byte = buf*32768 + ch*8192 + pt*256 + (k ^ ((pt&15)<<3))
    __shared__ __align__(16) unsigned char Hs[2][NCH][PBLK][HID];   // 64 KB
    __shared__ float red[8][5];

    const int tid   = threadIdx.x;
    const int wave  = tid >> 6;
    const int lane  = tid & 63;
    const int pt    = lane & 31;          // MFMA column = point / A row
    const int hi    = lane >> 5;
    const int pbase = blockIdx.x * PBLK;
    const int swz   = (pt & 15) << 3;

    // ---------------- layer 0: 2 -> 256 (fp32 VALU) ----------------
    {
        const int p0 = tid & 31;          // point
        const int c0 = (tid >> 5) * 16;   // 16 neurons per thread
        const int sz = (p0 & 15) << 3;
        float x = vect[(pbase + p0) * 2 + 0];
        float y = vect[(pbase + p0) * 2 + 1];
        #pragma unroll
        for (int jj = 0; jj < 2; ++jj) {
            const int cb = c0 + jj * 8;
            float4 wxa = *(const float4*)(W0 + cb);
            float4 wxb = *(const float4*)(W0 + cb + 4);
            float4 wya = *(const float4*)(W0 + HID + cb);
            float4 wyb = *(const float4*)(W0 + HID + cb + 4);
            float4 bba = *(const float4*)(b0 + cb);
            float4 bbb = *(const float4*)(b0 + cb + 4);
            float wx[8] = {wxa.x, wxa.y, wxa.z, wxa.w, wxb.x, wxb.y, wxb.z, wxb.w};
            float wy[8] = {wya.x, wya.y, wya.z, wya.w, wyb.x, wyb.y, wyb.z, wyb.w};
            float bb[8] = {bba.x, bba.y, bba.z, bba.w, bbb.x, bbb.y, bbb.z, bbb.w};
            float av[8], pv[8], mv[8], hv[8];
            #pragma unroll
            for (int q = 0; q < 8; ++q) {
                float z  = x * wx[q] + y * wy[q] + bb[q];
                float a  = fast_tanh(z);
                float s  = 1.0f - a * a;
                float gx = s * wx[q];
                float gy = s * wy[q];
                av[q] = a;
                pv[q] = gx + gy;
                mv[q] = gx - gy;
                hv[q] = -2.0f * a * (gx * wx[q] + gy * wy[q]);
            }
            const int idx = p0 * 256 + (cb ^ sz);
            *(uint2v*)&Hs[0][0][0][idx] = (uint2v){pk4_fp8(av[0],av[1],av[2],av[3]),
                                                   pk4_fp8(av[4],av[5],av[6],av[7])};
            *(uint2v*)&Hs[0][1][0][idx] = (uint2v){pk4_fp8(pv[0],pv[1],pv[2],pv[3]),
                                                   pk4_fp8(pv[4],pv[5],pv[6],pv[7])};
            *(uint2v*)&Hs[0][2][0][idx] = (uint2v){pk4_fp8(mv[0],mv[1],mv[2],mv[3]),
                                                   pk4_fp8(mv[4],mv[5],mv[6],mv[7])};
            *(uint2v*)&Hs[0][3][0][idx] = (uint2v){pk4_fp8(hv[0],hv[1],hv[2],hv[3]),
                                                   pk4_fp8(hv[4],hv[5],hv[6],hv[7])};
        }
    }
    __syncthreads();

    // ---------------- hidden layers 1..4: 32x32x16 fp8 MFMA (D = W * H^T) ----------------
    const float* bs[4] = {b1, b2, b3, b4};

    floatx16 zk = (floatx16)(0.0f);       // shared zero C-operand, init once

    #pragma unroll
    for (int L = 0; L < 4; ++L) {
        const int cur = L & 1;
        const int nxt = cur ^ 1;
        floatx16 acc[NCH];

        // A-frag: row = wave*32 + pt, k = ks*16 + hi*8 + j
        const unsigned char* wb = Wt + L * 65536 + ((wave << 5) + pt) * 256 + hi * 8;
        const unsigned char* hb = &Hs[cur][0][pt][0];     // ch stride 8192

        __builtin_amdgcn_s_setprio(1);
        #pragma unroll
        for (int ks = 0; ks < 16; ++ks) {
            const int ko = (ks * 16 + hi * 8) ^ swz;
            long long af  = *(const long long*)(wb + ks * 16);
            long long bf0 = *(const long long*)(hb + 0 * 8192 + ko);
            long long bf1 = *(const long long*)(hb + 1 * 8192 + ko);
            long long bf2 = *(const long long*)(hb + 2 * 8192 + ko);
            long long bf3 = *(const long long*)(hb + 3 * 8192 + ko);
            acc[0] = __builtin_amdgcn_mfma_f32_32x32x16_fp8_fp8(
                af, bf0, (ks == 0) ? zk : acc[0], 0, 0, 0);
            acc[1] = __builtin_amdgcn_mfma_f32_32x32x16_fp8_fp8(
                af, bf1, (ks == 0) ? zk : acc[1], 0, 0, 0);
            acc[2] = __builtin_amdgcn_mfma_f32_32x32x16_fp8_fp8(
                af, bf2, (ks == 0) ? zk : acc[2], 0, 0, 0);
            acc[3] = __builtin_amdgcn_mfma_f32_32x32x16_fp8_fp8(
                af, bf3, (ks == 0) ? zk : acc[3], 0, 0, 0);
        }
        __builtin_amdgcn_s_setprio(0);

        // epilogue (no barrier before: writes go to the other buffer)
        unsigned char* hw = &Hs[nxt][0][pt][0];
        #pragma unroll
        for (int q = 0; q < 4; ++q) {
            const int nq = (wave << 5) + q * 8 + hi * 4;
            float4 bb4 = *(const float4*)(bs[L] + nq);
            float bb[4] = {bb4.x, bb4.y, bb4.z, bb4.w};
            float av[4], pv[4], mv[4], hv[4];
            #pragma unroll
            for (int r = 0; r < 4; ++r) {
                const int reg = q * 4 + r;
                float z  = acc[0][reg] + bb[r];
                float a  = fast_tanh(z);
                float s  = 1.0f - a * a;
                float zp = acc[1][reg];
                float zm = acc[2][reg];
                float zh = acc[3][reg];
                av[r] = a;
                pv[r] = s * zp;
                mv[r] = s * zm;
                hv[r] = s * zh - a * s * (zp * zp + zm * zm);
            }
            const int kk = nq ^ swz;
            *(unsigned*)(hw + 0 * 8192 + kk) = pk4_fp8(av[0], av[1], av[2], av[3]);
            *(unsigned*)(hw + 1 * 8192 + kk) = pk4_fp8(pv[0], pv[1], pv[2], pv[3]);
            *(unsigned*)(hw + 2 * 8192 + kk) = pk4_fp8(mv[0], mv[1], mv[2], mv[3]);
            *(unsigned*)(hw + 3 * 8192 + kk) = pk4_fp8(hv[0], hv[1], hv[2], hv[3]);
        }
        __syncthreads();   // one barrier per layer
    }

    // ---------------- final layer 256 -> 1 + loss terms (reads buf 0) ----------------
    const int fp  = (wave << 2) + (lane >> 4);
    const int kc  = (lane & 15) * 16;
    const int fsz = (fp & 15) << 3;
    float sT = 0.f, sR = 0.f;
    #pragma unroll
    for (int j = 0; j < 2; ++j) {
        const int kb = kc + j * 8;
        const int ke = kb ^ fsz;
        uint2v hv = *(const uint2v*)(&Hs[0][0][fp][0] + ke);
        uint2v hh = *(const uint2v*)(&Hs[0][3][fp][0] + ke);
        float4 w5a = *(const float4*)(W5 + kb);
        float4 w5b = *(const float4*)(W5 + kb + 4);
        sT += __builtin_amdgcn_cvt_f32_fp8((int)hv.x, 0) * w5a.x
            + __builtin_amdgcn_cvt_f32_fp8((int)hv.x, 1) * w5a.y
            + __builtin_amdgcn_cvt_f32_fp8((int)hv.x, 2) * w5a.z
            + __builtin_amdgcn_cvt_f32_fp8((int)hv.x, 3) * w5a.w
            + __builtin_amdgcn_cvt_f32_fp8((int)hv.y, 0) * w5b.x
            + __builtin_amdgcn_cvt_f32_fp8((int)hv.y, 1) * w5b.y
            + __builtin_amdgcn_cvt_f32_fp8((int)hv.y, 2) * w5b.z
            + __builtin_amdgcn_cvt_f32_fp8((int)hv.y, 3) * w5b.w;
        sR += __builtin_amdgcn_cvt_f32_fp8((int)hh.x, 0) * w5a.x
            + __builtin_amdgcn_cvt_f32_fp8((int)hh.x, 1) * w5a.y
            + __builtin_amdgcn_cvt_f32_fp8((int)hh.x, 2) * w5a.z
            + __builtin_amdgcn_cvt_f32_fp8((int)hh.x, 3) * w5a.w
            + __builtin_amdgcn_cvt_f32_fp8((int)hh.y, 0) * w5b.x
            + __builtin_amdgcn_cvt_f32_fp8((int)hh.y, 1) * w5b.y
            + __builtin_amdgcn_cvt_f32_fp8((int)hh.y, 2) * w5b.z
            + __builtin_amdgcn_cvt_f32_fp8((int)hh.y, 3) * w5b.w;
    }
    // reduce across the 16 lanes sharing fp
    sT += __shfl_down(sT, 8, 64); sR += __shfl_down(sR, 8, 64);
    sT += __shfl_down(sT, 4, 64); sR += __shfl_down(sR, 4, 64);
    sT += __shfl_down(sT, 2, 64); sR += __shfl_down(sR, 2, 64);
    sT += __shfl_down(sT, 1, 64); sR += __shfl_down(sR, 1, 64);

    float r0 = 0.f, r1 = 0.f, r2 = 0.f, r3 = 0.f, r4 = 0.f;
    if ((lane & 15) == 0) {
        float T = sT + b5[0];
        r0 = sR * sR;
        int m = vals[pbase + fp];
        if (m == 1)      { float d = T - 1200.0f; r1 = d * d; r2 = 1.0f; }
        else if (m == 2) { float d = T - 25.0f;   r3 = d * d; r4 = 1.0f; }
    }
    #pragma unroll
    for (int off = 32; off >= 16; off >>= 1) {
        r0 += __shfl_down(r0, off, 64);
        r1 += __shfl_down(r1, off, 64);
        r2 += __shfl_down(r2, off, 64);
        r3 += __shfl_down(r3, off, 64);
        r4 += __shfl_down(r4, off, 64);
    }
    if (lane == 0) {
        red[wave][0] = r0; red[wave][1] = r1; red[wave][2] = r2;
        red[wave][3] = r3; red[wave][4] = r4;
    }
    __syncthreads();
    if (tid == 0) {
        #pragma unroll
        for (int c = 0; c < 5; ++c) {
            float s = 0.f;
            #pragma unroll
            for (int w = 0; w < 8; ++w) s += red[w][c];
            partials[blockIdx.x * 5 + c] = s;
        }
    }
}

__global__ __launch_bounds__(256) void pinn_reduce(const float* __restrict__ p,
                                                   float* __restrict__ out)
{
    float s[5] = {0.f, 0.f, 0.f, 0.f, 0.f};
    for (int idx = threadIdx.x; idx < NBLK; idx += 256) {
        #pragma unroll
        for (int c = 0; c < 5; ++c) s[c] += p[idx * 5 + c];
    }
    #pragma unroll
    for (int c = 0; c < 5; ++c) {
        #pragma unroll
        for (int off = 32; off > 0; off >>= 1)
            s[c] += __shfl_down(s[c], off, 64);
    }
    __shared__ float r[4][5];
    int wave = threadIdx.x >> 6;
    int lane = threadIdx.x & 63;
    if (lane == 0) {
        #pragma unroll
        for (int c = 0; c < 5; ++c) r[wave][c] = s[c];
    }
    __syncthreads();
    if (threadIdx.x == 0) {
        float t[5];
        #pragma unroll
        for (int c = 0; c < 5; ++c) t[c] = r[0][c] + r[1][c] + r[2][c] + r[3][c];
        out[0] = t[0] / (float)N_PTS
               + t[1] / fmaxf(t[2], 1.0f)
               + t[3] / fmaxf(t[4], 1.0f);
    }
}

extern "C" void kernel_launch(void* const* d_in, const int* in_sizes, int n_in,
                              void* d_out, int out_size, void* d_ws, size_t ws_size,
                              hipStream_t stream) {
    const float* vect = (const float*)d_in[0];
    const int*   vals = (const int*)d_in[1];
    const float* W0 = (const float*)d_in[2];
    const float* b0 = (const float*)d_in[3];
    const float* W1 = (const float*)d_in[4];
    const float* b1 = (const float*)d_in[5];
    const float* W2 = (const float*)d_in[6];
    const float* b2 = (const float*)d_in[7];
    const float* W3 = (const float*)d_in[8];
    const float* b3 = (const float*)d_in[9];
    const float* W4 = (const float*)d_in[10];
    const float* b4 = (const float*)d_in[11];
    const float* W5 = (const float*)d_in[12];
    const float* b5 = (const float*)d_in[13];

    float* partials    = (float*)d_ws;                     // 2048*5*4 = 40 KB
    unsigned char* Wt  = (unsigned char*)d_ws + 131072;    // 4*256*256 = 256 KB
    float* out         = (float*)d_out;

    conv_w<<<1024, 64, 0, stream>>>(W1, W2, W3, W4, Wt);
    pinn_main<<<NBLK, 512, 0, stream>>>(vect, vals, W0, b0, b1, b2, b3, b4,
                                        W5, b5, Wt, partials);
    pinn_reduce<<<1, 256, 0, stream>>>(partials, out);
}

// Round 9
// 147.280 us; speedup vs baseline: 2.0347x; 1.1536x over previous
//
#include <hip/hip_runtime.h>

#define N_PTS   65536
#define PBLK    32                 // points per block
#define NBLK    (N_PTS / PBLK)     // 2048 blocks
#define HID     256
#define NCH     4                  // v, p=gx+gy, m=gx-gy, h=hxx+hyy

typedef __attribute__((ext_vector_type(16))) float floatx16;  // 32x32 MFMA C/D
typedef __attribute__((ext_vector_type(8)))  int   int8v;     // 32-byte fp8 frag
typedef __attribute__((ext_vector_type(2)))  unsigned uint2v;

__device__ __forceinline__ float fast_tanh(float x) {
    float e = exp2f(2.885390082f * x);   // e^(2x) via v_exp_f32
    return 1.0f - 2.0f / (e + 1.0f);
}
// pack 4 f32 -> 4 fp8(e4m3) in one 32-bit word (2 cvt_pk instrs)
__device__ __forceinline__ unsigned pk4_fp8(float a, float b, float c, float d) {
    unsigned w = __builtin_amdgcn_cvt_pk_fp8_f32(a, b, 0, false);
    w = __builtin_amdgcn_cvt_pk_fp8_f32(c, d, (int)w, true);
    return w;
}

// ---- weight transpose+convert: Wt[L][n][k] = fp8(W_L[k][n]) ----
__global__ __launch_bounds__(64) void conv_w(
    const float* __restrict__ W1, const float* __restrict__ W2,
    const float* __restrict__ W3, const float* __restrict__ W4,
    unsigned char* __restrict__ Wt)
{
    int layer = blockIdx.x >> 8;
    int n     = blockIdx.x & 255;
    const float* W = (layer == 0) ? W1 : (layer == 1) ? W2 : (layer == 2) ? W3 : W4;
    int t = threadIdx.x;                      // word index: k = 4t..4t+3
    float a = W[(t * 4 + 0) * 256 + n];
    float b = W[(t * 4 + 1) * 256 + n];
    float c = W[(t * 4 + 2) * 256 + n];
    float d = W[(t * 4 + 3) * 256 + n];
    ((unsigned*)Wt)[((layer << 8) + n) * 64 + t] = pk4_fp8(a, b, c, d);
}

__global__ __launch_bounds__(512, 4) void pinn_main(
    const float* __restrict__ vect, const int* __restrict__ vals,
    const float* __restrict__ W0, const float* __restrict__ b0,
    const float* __restrict__ b1, const float* __restrict__ b2,
    const float* __restrict__ b3, const float* __restrict__ b4,
    const float* __restrict__ W5, const float* __restrict__ b5,
    const unsigned char* __restrict__ Wt, float* __restrict__ partials)
{
    // Hs[buf][ch][pt][k] fp8: byte = buf*32768 + ch*8192 + pt*256 + (k ^ ((pt&15)<<3))
    __shared__ __align__(16) unsigned char Hs[2][NCH][PBLK][HID];   // 64 KB
    __shared__ float red[8][5];

    const int tid   = threadIdx.x;
    const int wave  = tid >> 6;
    const int lane  = tid & 63;
    const int pt    = lane & 31;          // MFMA column = point / A row
    const int hi    = lane >> 5;
    const int pbase = blockIdx.x * PBLK;
    const int swz   = (pt & 15) << 3;

    // ---------------- layer 0: 2 -> 256 (fp32 VALU) ----------------
    {
        const int p0 = tid & 31;          // point
        const int c0 = (tid >> 5) * 16;   // 16 neurons per thread
        const int sz = (p0 & 15) << 3;
        float x = vect[(pbase + p0) * 2 + 0];
        float y = vect[(pbase + p0) * 2 + 1];
        #pragma unroll
        for (int jj = 0; jj < 2; ++jj) {
            const int cb = c0 + jj * 8;
            float4 wxa = *(const float4*)(W0 + cb);
            float4 wxb = *(const float4*)(W0 + cb + 4);
            float4 wya = *(const float4*)(W0 + HID + cb);
            float4 wyb = *(const float4*)(W0 + HID + cb + 4);
            float4 bba = *(const float4*)(b0 + cb);
            float4 bbb = *(const float4*)(b0 + cb + 4);
            float wx[8] = {wxa.x, wxa.y, wxa.z, wxa.w, wxb.x, wxb.y, wxb.z, wxb.w};
            float wy[8] = {wya.x, wya.y, wya.z, wya.w, wyb.x, wyb.y, wyb.z, wyb.w};
            float bb[8] = {bba.x, bba.y, bba.z, bba.w, bbb.x, bbb.y, bbb.z, bbb.w};
            float av[8], pv[8], mv[8], hv[8];
            #pragma unroll
            for (int q = 0; q < 8; ++q) {
                float z  = x * wx[q] + y * wy[q] + bb[q];
                float a  = fast_tanh(z);
                float s  = 1.0f - a * a;
                float gx = s * wx[q];
                float gy = s * wy[q];
                av[q] = a;
                pv[q] = gx + gy;
                mv[q] = gx - gy;
                hv[q] = -2.0f * a * (gx * wx[q] + gy * wy[q]);
            }
            const int idx = p0 * 256 + (cb ^ sz);
            *(uint2v*)&Hs[0][0][0][idx] = (uint2v){pk4_fp8(av[0],av[1],av[2],av[3]),
                                                   pk4_fp8(av[4],av[5],av[6],av[7])};
            *(uint2v*)&Hs[0][1][0][idx] = (uint2v){pk4_fp8(pv[0],pv[1],pv[2],pv[3]),
                                                   pk4_fp8(pv[4],pv[5],pv[6],pv[7])};
            *(uint2v*)&Hs[0][2][0][idx] = (uint2v){pk4_fp8(mv[0],mv[1],mv[2],mv[3]),
                                                   pk4_fp8(mv[4],mv[5],mv[6],mv[7])};
            *(uint2v*)&Hs[0][3][0][idx] = (uint2v){pk4_fp8(hv[0],hv[1],hv[2],hv[3]),
                                                   pk4_fp8(hv[4],hv[5],hv[6],hv[7])};
        }
    }
    __syncthreads();

    // ---------------- hidden layers 1..4: MX-scaled 32x32x64 fp8 MFMA ----------------
    const float* bs[4] = {b1, b2, b3, b4};

    floatx16 zk = (floatx16)(0.0f);       // zero C-operand, init once

    #pragma unroll
    for (int L = 0; L < 4; ++L) {
        const int cur = L & 1;
        const int nxt = cur ^ 1;
        floatx16 acc[NCH];

        // A-frag (W row = wave*32 + pt): 32 contiguous k-bytes at ks4*64 + hi*32
        const unsigned char* wb = Wt + L * 65536 + (((wave << 5) + pt) << 8) + (hi << 5);
        const unsigned char* hb = &Hs[cur][0][pt][0];     // ch stride 8192

        __builtin_amdgcn_s_setprio(1);
        #pragma unroll
        for (int ks4 = 0; ks4 < 4; ++ks4) {
            const int kb = ks4 * 64 + (hi << 5);          // lane's k-window (unswizzled)
            union { int8v v; int4 d[2]; } af;
            af.d[0] = *(const int4*)(wb + ks4 * 64);
            af.d[1] = *(const int4*)(wb + ks4 * 64 + 16);
            union { int8v v; long long q[4]; } bf[NCH];
            #pragma unroll
            for (int ch = 0; ch < NCH; ++ch) {
                #pragma unroll
                for (int j = 0; j < 4; ++j)
                    bf[ch].q[j] = *(const long long*)(hb + ch * 8192 + ((kb + j * 8) ^ swz));
            }
            acc[0] = __builtin_amdgcn_mfma_scale_f32_32x32x64_f8f6f4(
                af.v, bf[0].v, (ks4 == 0) ? zk : acc[0], 0, 0, 0, 0x7F, 0, 0x7F);
            acc[1] = __builtin_amdgcn_mfma_scale_f32_32x32x64_f8f6f4(
                af.v, bf[1].v, (ks4 == 0) ? zk : acc[1], 0, 0, 0, 0x7F, 0, 0x7F);
            acc[2] = __builtin_amdgcn_mfma_scale_f32_32x32x64_f8f6f4(
                af.v, bf[2].v, (ks4 == 0) ? zk : acc[2], 0, 0, 0, 0x7F, 0, 0x7F);
            acc[3] = __builtin_amdgcn_mfma_scale_f32_32x32x64_f8f6f4(
                af.v, bf[3].v, (ks4 == 0) ? zk : acc[3], 0, 0, 0, 0x7F, 0, 0x7F);
        }
        __builtin_amdgcn_s_setprio(0);

        // epilogue (writes go to the other buffer; single barrier per layer)
        unsigned char* hw = &Hs[nxt][0][pt][0];
        #pragma unroll
        for (int q = 0; q < 4; ++q) {
            const int nq = (wave << 5) + q * 8 + hi * 4;
            float4 bb4 = *(const float4*)(bs[L] + nq);
            float bb[4] = {bb4.x, bb4.y, bb4.z, bb4.w};
            float av[4], pv[4], mv[4], hv[4];
            #pragma unroll
            for (int r = 0; r < 4; ++r) {
                const int reg = q * 4 + r;
                float z  = acc[0][reg] + bb[r];
                float a  = fast_tanh(z);
                float s  = 1.0f - a * a;
                float zp = acc[1][reg];
                float zm = acc[2][reg];
                float zh = acc[3][reg];
                av[r] = a;
                pv[r] = s * zp;
                mv[r] = s * zm;
                hv[r] = s * zh - a * s * (zp * zp + zm * zm);
            }
            const int kk = nq ^ swz;
            *(unsigned*)(hw + 0 * 8192 + kk) = pk4_fp8(av[0], av[1], av[2], av[3]);
            *(unsigned*)(hw + 1 * 8192 + kk) = pk4_fp8(pv[0], pv[1], pv[2], pv[3]);
            *(unsigned*)(hw + 2 * 8192 + kk) = pk4_fp8(mv[0], mv[1], mv[2], mv[3]);
            *(unsigned*)(hw + 3 * 8192 + kk) = pk4_fp8(hv[0], hv[1], hv[2], hv[3]);
        }
        __syncthreads();   // one barrier per layer
    }

    // ---------------- final layer 256 -> 1 + loss terms (reads buf 0) ----------------
    const int fp  = (wave << 2) + (lane >> 4);
    const int kc  = (lane & 15) * 16;
    const int fsz = (fp & 15) << 3;
    float sT = 0.f, sR = 0.f;
    #pragma unroll
    for (int j = 0; j < 2; ++j) {
        const int kb = kc + j * 8;
        const int ke = kb ^ fsz;
        uint2v hv = *(const uint2v*)(&Hs[0][0][fp][0] + ke);
        uint2v hh = *(const uint2v*)(&Hs[0][3][fp][0] + ke);
        float4 w5a = *(const float4*)(W5 + kb);
        float4 w5b = *(const float4*)(W5 + kb + 4);
        sT += __builtin_amdgcn_cvt_f32_fp8((int)hv.x, 0) * w5a.x
            + __builtin_amdgcn_cvt_f32_fp8((int)hv.x, 1) * w5a.y
            + __builtin_amdgcn_cvt_f32_fp8((int)hv.x, 2) * w5a.z
            + __builtin_amdgcn_cvt_f32_fp8((int)hv.x, 3) * w5a.w
            + __builtin_amdgcn_cvt_f32_fp8((int)hv.y, 0) * w5b.x
            + __builtin_amdgcn_cvt_f32_fp8((int)hv.y, 1) * w5b.y
            + __builtin_amdgcn_cvt_f32_fp8((int)hv.y, 2) * w5b.z
            + __builtin_amdgcn_cvt_f32_fp8((int)hv.y, 3) * w5b.w;
        sR += __builtin_amdgcn_cvt_f32_fp8((int)hh.x, 0) * w5a.x
            + __builtin_amdgcn_cvt_f32_fp8((int)hh.x, 1) * w5a.y
            + __builtin_amdgcn_cvt_f32_fp8((int)hh.x, 2) * w5a.z
            + __builtin_amdgcn_cvt_f32_fp8((int)hh.x, 3) * w5a.w
            + __builtin_amdgcn_cvt_f32_fp8((int)hh.y, 0) * w5b.x
            + __builtin_amdgcn_cvt_f32_fp8((int)hh.y, 1) * w5b.y
            + __builtin_amdgcn_cvt_f32_fp8((int)hh.y, 2) * w5b.z
            + __builtin_amdgcn_cvt_f32_fp8((int)hh.y, 3) * w5b.w;
    }
    sT += __shfl_down(sT, 8, 64); sR += __shfl_down(sR, 8, 64);
    sT += __shfl_down(sT, 4, 64); sR += __shfl_down(sR, 4, 64);
    sT += __shfl_down(sT, 2, 64); sR += __shfl_down(sR, 2, 64);
    sT += __shfl_down(sT, 1, 64); sR += __shfl_down(sR, 1, 64);

    float r0 = 0.f, r1 = 0.f, r2 = 0.f, r3 = 0.f, r4 = 0.f;
    if ((lane & 15) == 0) {
        float T = sT + b5[0];
        r0 = sR * sR;
        int m = vals[pbase + fp];
        if (m == 1)      { float d = T - 1200.0f; r1 = d * d; r2 = 1.0f; }
        else if (m == 2) { float d = T - 25.0f;   r3 = d * d; r4 = 1.0f; }
    }
    #pragma unroll
    for (int off = 32; off >= 16; off >>= 1) {
        r0 += __shfl_down(r0, off, 64);
        r1 += __shfl_down(r1, off, 64);
        r2 += __shfl_down(r2, off, 64);
        r3 += __shfl_down(r3, off, 64);
        r4 += __shfl_down(r4, off, 64);
    }
    if (lane == 0) {
        red[wave][0] = r0; red[wave][1] = r1; red[wave][2] = r2;
        red[wave][3] = r3; red[wave][4] = r4;
    }
    __syncthreads();
    if (tid == 0) {
        #pragma unroll
        for (int c = 0; c < 5; ++c) {
            float s = 0.f;
            #pragma unroll
            for (int w = 0; w < 8; ++w) s += red[w][c];
            partials[blockIdx.x * 5 + c] = s;
        }
    }
}

__global__ __launch_bounds__(256) void pinn_reduce(const float* __restrict__ p,
                                                   float* __restrict__ out)
{
    float s[5] = {0.f, 0.f, 0.f, 0.f, 0.f};
    for (int idx = threadIdx.x; idx < NBLK; idx += 256) {
        #pragma unroll
        for (int c = 0; c < 5; ++c) s[c] += p[idx * 5 + c];
    }
    #pragma unroll
    for (int c = 0; c < 5; ++c) {
        #pragma unroll
        for (int off = 32; off > 0; off >>= 1)
            s[c] += __shfl_down(s[c], off, 64);
    }
    __shared__ float r[4][5];
    int wave = threadIdx.x >> 6;
    int lane = threadIdx.x & 63;
    if (lane == 0) {
        #pragma unroll
        for (int c = 0; c < 5; ++c) r[wave][c] = s[c];
    }
    __syncthreads();
    if (threadIdx.x == 0) {
        float t[5];
        #pragma unroll
        for (int c = 0; c < 5; ++c) t[c] = r[0][c] + r[1][c] + r[2][c] + r[3][c];
        out[0] = t[0] / (float)N_PTS
               + t[1] / fmaxf(t[2], 1.0f)
               + t[3] / fmaxf(t[4], 1.0f);
    }
}

extern "C" void kernel_launch(void* const* d_in, const int* in_sizes, int n_in,
                              void* d_out, int out_size, void* d_ws, size_t ws_size,
                              hipStream_t stream) {
    const float* vect = (const float*)d_in[0];
    const int*   vals = (const int*)d_in[1];
    const float* W0 = (const float*)d_in[2];
    const float* b0 = (const float*)d_in[3];
    const float* W1 = (const float*)d_in[4];
    const float* b1 = (const float*)d_in[5];
    const float* W2 = (const float*)d_in[6];
    const float* b2 = (const float*)d_in[7];
    const float* W3 = (const float*)d_in[8];
    const float* b3 = (const float*)d_in[9];
    const float* W4 = (const float*)d_in[10];
    const float* b4 = (const float*)d_in[11];
    const float* W5 = (const float*)d_in[12];
    const float* b5 = (const float*)d_in[13];

    float* partials    = (float*)d_ws;                     // 2048*5*4 = 40 KB
    unsigned char* Wt  = (unsigned char*)d_ws + 131072;    // 4*256*256 = 256 KB
    float* out         = (float*)d_out;

    conv_w<<<1024, 64, 0, stream>>>(W1, W2, W3, W4, Wt);
    pinn_main<<<NBLK, 512, 0, stream>>>(vect, vals, W0, b0, b1, b2, b3, b4,
                                        W5, b5, Wt, partials);
    pinn_reduce<<<1, 256, 0, stream>>>(partials, out);
}

// Round 10
// 135.054 us; speedup vs baseline: 2.2189x; 1.0905x over previous
//
#include <hip/hip_runtime.h>

#define N_PTS   65536
#define PBLK    32                 // points per block
#define NBLK    (N_PTS / PBLK)     // 2048 blocks
#define HID     256
#define NCH     4                  // v, p=gx+gy, m=gx-gy, h=hxx+hyy

typedef __attribute__((ext_vector_type(16))) float floatx16;  // 32x32 MFMA C/D
typedef __attribute__((ext_vector_type(8)))  int   int8v;     // 32-byte fp8 frag
typedef __attribute__((ext_vector_type(4)))  long long llx4;  // 32-byte as 4x b64
typedef __attribute__((ext_vector_type(2)))  unsigned uint2v;

__device__ __forceinline__ float fast_tanh(float x) {
    float e = exp2f(2.885390082f * x);   // e^(2x) via v_exp_f32
    return 1.0f - 2.0f / (e + 1.0f);
}
// pack 4 f32 -> 4 fp8(e4m3) in one 32-bit word (2 cvt_pk instrs)
__device__ __forceinline__ unsigned pk4_fp8(float a, float b, float c, float d) {
    unsigned w = __builtin_amdgcn_cvt_pk_fp8_f32(a, b, 0, false);
    w = __builtin_amdgcn_cvt_pk_fp8_f32(c, d, (int)w, true);
    return w;
}

// ---- weight transpose+convert: Wt[L][n][k] = fp8(W_L[k][n]) ----
__global__ __launch_bounds__(64) void conv_w(
    const float* __restrict__ W1, const float* __restrict__ W2,
    const float* __restrict__ W3, const float* __restrict__ W4,
    unsigned char* __restrict__ Wt)
{
    int layer = blockIdx.x >> 8;
    int n     = blockIdx.x & 255;
    const float* W = (layer == 0) ? W1 : (layer == 1) ? W2 : (layer == 2) ? W3 : W4;
    int t = threadIdx.x;                      // word index: k = 4t..4t+3
    float a = W[(t * 4 + 0) * 256 + n];
    float b = W[(t * 4 + 1) * 256 + n];
    float c = W[(t * 4 + 2) * 256 + n];
    float d = W[(t * 4 + 3) * 256 + n];
    ((unsigned*)Wt)[((layer << 8) + n) * 64 + t] = pk4_fp8(a, b, c, d);
}

__global__ __launch_bounds__(512, 4) void pinn_main(
    const float* __restrict__ vect, const int* __restrict__ vals,
    const float* __restrict__ W0, const float* __restrict__ b0,
    const float* __restrict__ b1, const float* __restrict__ b2,
    const float* __restrict__ b3, const float* __restrict__ b4,
    const float* __restrict__ W5, const float* __restrict__ b5,
    const unsigned char* __restrict__ Wt, float* __restrict__ partials)
{
    // Hs[buf][ch][pt][k] fp8: byte = buf*32768 + ch*8192 + pt*256 + (k ^ ((pt&15)<<3))
    __shared__ __align__(16) unsigned char Hs[2][NCH][PBLK][HID];   // 64 KB
    __shared__ float red[8][5];

    const int tid   = threadIdx.x;
    const int wave  = tid >> 6;
    const int lane  = tid & 63;
    const int pt    = lane & 31;          // MFMA column = point / A row
    const int hi    = lane >> 5;
    const int pbase = blockIdx.x * PBLK;
    const int swz   = (pt & 15) << 3;

    // ---------------- layer 0: 2 -> 256 (fp32 VALU) ----------------
    {
        const int p0 = tid & 31;          // point
        const int c0 = (tid >> 5) * 16;   // 16 neurons per thread
        const int sz = (p0 & 15) << 3;
        float x = vect[(pbase + p0) * 2 + 0];
        float y = vect[(pbase + p0) * 2 + 1];
        #pragma unroll
        for (int jj = 0; jj < 2; ++jj) {
            const int cb = c0 + jj * 8;
            float4 wxa = *(const float4*)(W0 + cb);
            float4 wxb = *(const float4*)(W0 + cb + 4);
            float4 wya = *(const float4*)(W0 + HID + cb);
            float4 wyb = *(const float4*)(W0 + HID + cb + 4);
            float4 bba = *(const float4*)(b0 + cb);
            float4 bbb = *(const float4*)(b0 + cb + 4);
            float wx[8] = {wxa.x, wxa.y, wxa.z, wxa.w, wxb.x, wxb.y, wxb.z, wxb.w};
            float wy[8] = {wya.x, wya.y, wya.z, wya.w, wyb.x, wyb.y, wyb.z, wyb.w};
            float bb[8] = {bba.x, bba.y, bba.z, bba.w, bbb.x, bbb.y, bbb.z, bbb.w};
            float av[8], pv[8], mv[8], hv[8];
            #pragma unroll
            for (int q = 0; q < 8; ++q) {
                float z  = x * wx[q] + y * wy[q] + bb[q];
                float a  = fast_tanh(z);
                float s  = 1.0f - a * a;
                float gx = s * wx[q];
                float gy = s * wy[q];
                av[q] = a;
                pv[q] = gx + gy;
                mv[q] = gx - gy;
                hv[q] = -2.0f * a * (gx * wx[q] + gy * wy[q]);
            }
            const int idx = p0 * 256 + (cb ^ sz);
            *(uint2v*)&Hs[0][0][0][idx] = (uint2v){pk4_fp8(av[0],av[1],av[2],av[3]),
                                                   pk4_fp8(av[4],av[5],av[6],av[7])};
            *(uint2v*)&Hs[0][1][0][idx] = (uint2v){pk4_fp8(pv[0],pv[1],pv[2],pv[3]),
                                                   pk4_fp8(pv[4],pv[5],pv[6],pv[7])};
            *(uint2v*)&Hs[0][2][0][idx] = (uint2v){pk4_fp8(mv[0],mv[1],mv[2],mv[3]),
                                                   pk4_fp8(mv[4],mv[5],mv[6],mv[7])};
            *(uint2v*)&Hs[0][3][0][idx] = (uint2v){pk4_fp8(hv[0],hv[1],hv[2],hv[3]),
                                                   pk4_fp8(hv[4],hv[5],hv[6],hv[7])};
        }
    }
    __syncthreads();

    // ---------------- hidden layers 1..4: MX-scaled 32x32x64 fp8 MFMA ----------------
    const float* bs[4] = {b1, b2, b3, b4};

    floatx16 zk = (floatx16)(0.0f);       // zero C-operand, init once

    #pragma unroll
    for (int L = 0; L < 4; ++L) {
        const int cur = L & 1;
        const int nxt = cur ^ 1;
        floatx16 acc[NCH];

        // A-frag (W row = wave*32 + pt): 32 contiguous k-bytes at ks4*64 + hi*32
        const unsigned char* wb = Wt + L * 65536 + (((wave << 5) + pt) << 8) + (hi << 5);
        const unsigned char* hb = &Hs[cur][0][pt][0];     // ch stride 8192

        __builtin_amdgcn_s_setprio(1);
        #pragma unroll
        for (int ks4 = 0; ks4 < 4; ++ks4) {
            const int kb = ks4 * 64 + (hi << 5);          // lane's k-window (unswizzled)
            // A fragment: register-resident vector build (no union -> no scratch)
            int4 a0 = *(const int4*)(wb + ks4 * 64);
            int4 a1 = *(const int4*)(wb + ks4 * 64 + 16);
            int8v af;
            af[0] = a0.x; af[1] = a0.y; af[2] = a0.z; af[3] = a0.w;
            af[4] = a1.x; af[5] = a1.y; af[6] = a1.z; af[7] = a1.w;
            #pragma unroll
            for (int ch = 0; ch < NCH; ++ch) {
                llx4 t;
                t[0] = *(const long long*)(hb + ch * 8192 + ((kb +  0) ^ swz));
                t[1] = *(const long long*)(hb + ch * 8192 + ((kb +  8) ^ swz));
                t[2] = *(const long long*)(hb + ch * 8192 + ((kb + 16) ^ swz));
                t[3] = *(const long long*)(hb + ch * 8192 + ((kb + 24) ^ swz));
                int8v bfv = __builtin_bit_cast(int8v, t);
                acc[ch] = __builtin_amdgcn_mfma_scale_f32_32x32x64_f8f6f4(
                    af, bfv, (ks4 == 0) ? zk : acc[ch], 0, 0, 0, 0x7F, 0, 0x7F);
            }
        }
        __builtin_amdgcn_s_setprio(0);

        // epilogue (writes go to the other buffer; single barrier per layer)
        unsigned char* hw = &Hs[nxt][0][pt][0];
        #pragma unroll
        for (int q = 0; q < 4; ++q) {
            const int nq = (wave << 5) + q * 8 + hi * 4;
            float4 bb4 = *(const float4*)(bs[L] + nq);
            float bb[4] = {bb4.x, bb4.y, bb4.z, bb4.w};
            float av[4], pv[4], mv[4], hv[4];
            #pragma unroll
            for (int r = 0; r < 4; ++r) {
                const int reg = q * 4 + r;
                float z  = acc[0][reg] + bb[r];
                float a  = fast_tanh(z);
                float s  = 1.0f - a * a;
                float zp = acc[1][reg];
                float zm = acc[2][reg];
                float zh = acc[3][reg];
                av[r] = a;
                pv[r] = s * zp;
                mv[r] = s * zm;
                hv[r] = s * zh - a * s * (zp * zp + zm * zm);
            }
            const int kk = nq ^ swz;
            *(unsigned*)(hw + 0 * 8192 + kk) = pk4_fp8(av[0], av[1], av[2], av[3]);
            *(unsigned*)(hw + 1 * 8192 + kk) = pk4_fp8(pv[0], pv[1], pv[2], pv[3]);
            *(unsigned*)(hw + 2 * 8192 + kk) = pk4_fp8(mv[0], mv[1], mv[2], mv[3]);
            *(unsigned*)(hw + 3 * 8192 + kk) = pk4_fp8(hv[0], hv[1], hv[2], hv[3]);
        }
        __syncthreads();   // one barrier per layer
    }

    // ---------------- final layer 256 -> 1 + loss terms (reads buf 0) ----------------
    const int fp  = (wave << 2) + (lane >> 4);
    const int kc  = (lane & 15) * 16;
    const int fsz = (fp & 15) << 3;
    float sT = 0.f, sR = 0.f;
    #pragma unroll
    for (int j = 0; j < 2; ++j) {
        const int kb = kc + j * 8;
        const int ke = kb ^ fsz;
        uint2v hv = *(const uint2v*)(&Hs[0][0][fp][0] + ke);
        uint2v hh = *(const uint2v*)(&Hs[0][3][fp][0] + ke);
        float4 w5a = *(const float4*)(W5 + kb);
        float4 w5b = *(const float4*)(W5 + kb + 4);
        sT += __builtin_amdgcn_cvt_f32_fp8((int)hv.x, 0) * w5a.x
            + __builtin_amdgcn_cvt_f32_fp8((int)hv.x, 1) * w5a.y
            + __builtin_amdgcn_cvt_f32_fp8((int)hv.x, 2) * w5a.z
            + __builtin_amdgcn_cvt_f32_fp8((int)hv.x, 3) * w5a.w
            + __builtin_amdgcn_cvt_f32_fp8((int)hv.y, 0) * w5b.x
            + __builtin_amdgcn_cvt_f32_fp8((int)hv.y, 1) * w5b.y
            + __builtin_amdgcn_cvt_f32_fp8((int)hv.y, 2) * w5b.z
            + __builtin_amdgcn_cvt_f32_fp8((int)hv.y, 3) * w5b.w;
        sR += __builtin_amdgcn_cvt_f32_fp8((int)hh.x, 0) * w5a.x
            + __builtin_amdgcn_cvt_f32_fp8((int)hh.x, 1) * w5a.y
            + __builtin_amdgcn_cvt_f32_fp8((int)hh.x, 2) * w5a.z
            + __builtin_amdgcn_cvt_f32_fp8((int)hh.x, 3) * w5a.w
            + __builtin_amdgcn_cvt_f32_fp8((int)hh.y, 0) * w5b.x
            + __builtin_amdgcn_cvt_f32_fp8((int)hh.y, 1) * w5b.y
            + __builtin_amdgcn_cvt_f32_fp8((int)hh.y, 2) * w5b.z
            + __builtin_amdgcn_cvt_f32_fp8((int)hh.y, 3) * w5b.w;
    }
    sT += __shfl_down(sT, 8, 64); sR += __shfl_down(sR, 8, 64);
    sT += __shfl_down(sT, 4, 64); sR += __shfl_down(sR, 4, 64);
    sT += __shfl_down(sT, 2, 64); sR += __shfl_down(sR, 2, 64);
    sT += __shfl_down(sT, 1, 64); sR += __shfl_down(sR, 1, 64);

    float r0 = 0.f, r1 = 0.f, r2 = 0.f, r3 = 0.f, r4 = 0.f;
    if ((lane & 15) == 0) {
        float T = sT + b5[0];
        r0 = sR * sR;
        int m = vals[pbase + fp];
        if (m == 1)      { float d = T - 1200.0f; r1 = d * d; r2 = 1.0f; }
        else if (m == 2) { float d = T - 25.0f;   r3 = d * d; r4 = 1.0f; }
    }
    #pragma unroll
    for (int off = 32; off >= 16; off >>= 1) {
        r0 += __shfl_down(r0, off, 64);
        r1 += __shfl_down(r1, off, 64);
        r2 += __shfl_down(r2, off, 64);
        r3 += __shfl_down(r3, off, 64);
        r4 += __shfl_down(r4, off, 64);
    }
    if (lane == 0) {
        red[wave][0] = r0; red[wave][1] = r1; red[wave][2] = r2;
        red[wave][3] = r3; red[wave][4] = r4;
    }
    __syncthreads();
    if (tid == 0) {
        #pragma unroll
        for (int c = 0; c < 5; ++c) {
            float s = 0.f;
            #pragma unroll
            for (int w = 0; w < 8; ++w) s += red[w][c];
            partials[blockIdx.x * 5 + c] = s;
        }
    }
}

__global__ __launch_bounds__(256) void pinn_reduce(const float* __restrict__ p,
                                                   float* __restrict__ out)
{
    float s[5] = {0.f, 0.f, 0.f, 0.f, 0.f};
    for (int idx = threadIdx.x; idx < NBLK; idx += 256) {
        #pragma unroll
        for (int c = 0; c < 5; ++c) s[c] += p[idx * 5 + c];
    }
    #pragma unroll
    for (int c = 0; c < 5; ++c) {
        #pragma unroll
        for (int off = 32; off > 0; off >>= 1)
            s[c] += __shfl_down(s[c], off, 64);
    }
    __shared__ float r[4][5];
    int wave = threadIdx.x >> 6;
    int lane = threadIdx.x & 63;
    if (lane == 0) {
        #pragma unroll
        for (int c = 0; c < 5; ++c) r[wave][c] = s[c];
    }
    __syncthreads();
    if (threadIdx.x == 0) {
        float t[5];
        #pragma unroll
        for (int c = 0; c < 5; ++c) t[c] = r[0][c] + r[1][c] + r[2][c] + r[3][c];
        out[0] = t[0] / (float)N_PTS
               + t[1] / fmaxf(t[2], 1.0f)
               + t[3] / fmaxf(t[4], 1.0f);
    }
}

extern "C" void kernel_launch(void* const* d_in, const int* in_sizes, int n_in,
                              void* d_out, int out_size, void* d_ws, size_t ws_size,
                              hipStream_t stream) {
    const float* vect = (const float*)d_in[0];
    const int*   vals = (const int*)d_in[1];
    const float* W0 = (const float*)d_in[2];
    const float* b0 = (const float*)d_in[3];
    const float* W1 = (const float*)d_in[4];
    const float* b1 = (const float*)d_in[5];
    const float* W2 = (const float*)d_in[6];
    const float* b2 = (const float*)d_in[7];
    const float* W3 = (const float*)d_in[8];
    const float* b3 = (const float*)d_in[9];
    const float* W4 = (const float*)d_in[10];
    const float* b4 = (const float*)d_in[11];
    const float* W5 = (const float*)d_in[12];
    const float* b5 = (const float*)d_in[13];

    float* partials    = (float*)d_ws;                     // 2048*5*4 = 40 KB
    unsigned char* Wt  = (unsigned char*)d_ws + 131072;    // 4*256*256 = 256 KB
    float* out         = (float*)d_out;

    conv_w<<<1024, 64, 0, stream>>>(W1, W2, W3, W4, Wt);
    pinn_main<<<NBLK, 512, 0, stream>>>(vect, vals, W0, b0, b1, b2, b3, b4,
                                        W5, b5, Wt, partials);
    pinn_reduce<<<1, 256, 0, stream>>>(partials, out);
}